// Round 12
// baseline (256.811 us; speedup 1.0000x reference)
//
#include <hip/hip_runtime.h>
#include <hip/hip_bf16.h>
#include <stdint.h>

#define B_   2
#define T_   2048
#define H_   2048
#define NH_  16
#define NKV_ 4
#define HD_  128
#define M_   (B_*T_)
#define SCALE_  0.08838834764831845f
#define SCALE2_ (0.08838834764831845f * 1.4426950408889634f)   // scale * log2(e)

typedef __hip_bfloat16 bf16;
typedef __attribute__((ext_vector_type(8))) short bh8;
typedef __attribute__((ext_vector_type(4))) float f32x4;
typedef __attribute__((ext_vector_type(4))) unsigned short us4;

__device__ __forceinline__ void gload16(const bf16* g, bf16* l) {
  __builtin_amdgcn_global_load_lds(
      (const __attribute__((address_space(1))) void*)g,
      (__attribute__((address_space(3))) void*)l, 16, 0, 0);
}

__device__ __forceinline__ void cstore(bf16* p, float v)  { *p = __float2bfloat16(v); }
__device__ __forceinline__ void cstore(float* p, float v) { *p = v; }

// fp32 -> bf16 elementwise (n multiple of 8)
__global__ __launch_bounds__(256) void cvt32to16(const float* __restrict__ src,
                                                 bf16* __restrict__ dst, int n)
{
  const int stride = gridDim.x * 256 * 8;
  for (int i = (blockIdx.x * 256 + threadIdx.x) * 8; i < n; i += stride) {
    const float4 a = *(const float4*)(src + i);
    const float4 b = *(const float4*)(src + i + 4);
    bf16 o[8];
    o[0]=__float2bfloat16(a.x); o[1]=__float2bfloat16(a.y);
    o[2]=__float2bfloat16(a.z); o[3]=__float2bfloat16(a.w);
    o[4]=__float2bfloat16(b.x); o[5]=__float2bfloat16(b.y);
    o[6]=__float2bfloat16(b.z); o[7]=__float2bfloat16(b.w);
    *(bh8*)(dst + i) = *(const bh8*)o;
  }
}

// Generic GEMM body: C[m][n] = sum_k A[m][k]*Bm[n][k], 128x128 tile, BK=64.
template<typename OutT>
__device__ __forceinline__ void gemm_body(
    const bf16* __restrict__ A, const bf16* __restrict__ Bm, OutT* __restrict__ Cm,
    int N, int K, int m0, int n0,
    bf16* As, bf16* Bs)
{
  const int tid  = threadIdx.x;
  const int lane = tid & 63;
  const int w    = tid >> 6;
  const int wr   = w >> 1, wc = w & 1;
  const int l15  = lane & 15;
  const int lk   = (lane >> 4) * 8;
  const int srow = lane >> 3;
  const int scol = (lane & 7) * 8;

  f32x4 acc[4][4] = {};

  for (int k0 = 0; k0 < K; k0 += 64) {
    #pragma unroll
    for (int i = 0; i < 4; ++i) {
      const int chunk = w*4 + i;
      const int row   = chunk*8 + srow;
      gload16(A  + (size_t)(m0+row)*K + k0 + scol, &As[chunk*512 + lane*8]);
      gload16(Bm + (size_t)(n0+row)*K + k0 + scol, &Bs[chunk*512 + lane*8]);
    }
    asm volatile("s_waitcnt vmcnt(0)" ::: "memory");
    __syncthreads();
    #pragma unroll
    for (int kk = 0; kk < 2; ++kk) {
      bh8 af[4], bfr[4];
      #pragma unroll
      for (int mi=0;mi<4;mi++) af[mi]  = *(const bh8*)&As[(wr*64 + mi*16 + l15)*64 + kk*32 + lk];
      #pragma unroll
      for (int nj=0;nj<4;nj++) bfr[nj] = *(const bh8*)&Bs[(wc*64 + nj*16 + l15)*64 + kk*32 + lk];
      #pragma unroll
      for (int mi=0;mi<4;mi++)
        #pragma unroll
        for (int nj=0;nj<4;nj++)
          acc[mi][nj] = __builtin_amdgcn_mfma_f32_16x16x32_bf16(af[mi], bfr[nj], acc[mi][nj], 0,0,0);
    }
    __syncthreads();
  }

  #pragma unroll
  for (int mi=0;mi<4;mi++)
    #pragma unroll
    for (int r=0;r<4;r++) {
      const int row = m0 + wr*64 + mi*16 + (lane>>4)*4 + r;
      #pragma unroll
      for (int nj=0;nj<4;nj++) {
        const int col = n0 + wc*64 + nj*16 + l15;
        cstore(&Cm[(size_t)row*N + col], acc[mi][nj][r]);
      }
    }
}

// Fused QKV projections: 768 blocks = 512 Q + 128 K + 128 V = exactly 3/CU.
__global__ __launch_bounds__(256) void gemm_qkv(
    const bf16* __restrict__ A,
    const bf16* __restrict__ Wqb, const bf16* __restrict__ Wkb, const bf16* __restrict__ Wvb,
    bf16* __restrict__ Cq, bf16* __restrict__ Ck, bf16* __restrict__ Cv)
{
  __shared__ bf16 As[128*64];
  __shared__ bf16 Bs[128*64];
  const int id = blockIdx.x;
  const bf16* Bm; bf16* Cm; int N, n0, m0;
  if (id < 512)      {                   Bm=Wqb; Cm=Cq; N=2048; n0=(id&15)<<7; m0=(id>>4)<<7; }
  else if (id < 640) { const int t=id-512; Bm=Wkb; Cm=Ck; N=512; n0=(t&3)<<7; m0=(t>>2)<<7; }
  else               { const int t=id-640; Bm=Wvb; Cm=Cv; N=512; n0=(t&3)<<7; m0=(t>>2)<<7; }
  gemm_body<bf16>(A, Bm, Cm, N, 2048, m0, n0, As, Bs);
}

// O projection (fp32 out)
__global__ __launch_bounds__(256) void gemm_o(
    const bf16* __restrict__ A, const bf16* __restrict__ Wob, float* __restrict__ C)
{
  __shared__ bf16 As[128*64];
  __shared__ bf16 Bs[128*64];
  gemm_body<float>(A, Wob, C, H_, NH_*HD_, (int)(blockIdx.y<<7), (int)(blockIdx.x<<7), As, Bs);
}

// Per (b,t): RMSNorm(HD) + RoPE IN PLACE. Lane l owns d=l and d=l+64.
__global__ __launch_bounds__(256) void postproc(
    bf16* __restrict__ q, bf16* __restrict__ k,
    const float* __restrict__ qw, const float* __restrict__ kw)
{
  const int blk  = blockIdx.x;
  const int t    = blk & (T_-1);
  const int lane = threadIdx.x & 63;
  const int w    = threadIdx.x >> 6;

  const float inv = expf(-(float)lane * (9.210340371976184f / 64.f));
  const float ang = (float)t * inv;
  const float cw = cosf(ang), sw = sinf(ang);

  #pragma unroll
  for (int hi = 0; hi < 4; ++hi) {
    const int h = w + hi*4;
    bf16* row = q + (size_t)blk*(NH_*HD_) + h*HD_;
    float x1 = __bfloat162float(row[lane]);
    float x2 = __bfloat162float(row[lane+64]);
    float ss = x1*x1 + x2*x2;
    #pragma unroll
    for (int m = 1; m < 64; m <<= 1) ss += __shfl_xor(ss, m, 64);
    const float rs = rsqrtf(ss*(1.f/128.f) + 1e-6f);
    const float n1 = x1*rs*(1.f + qw[lane]), n2 = x2*rs*(1.f + qw[lane+64]);
    row[lane]    = __float2bfloat16(n1*cw - n2*sw);
    row[lane+64] = __float2bfloat16(n2*cw + n1*sw);
  }
  {
    bf16* row = k + (size_t)blk*(NKV_*HD_) + w*HD_;
    float x1 = __bfloat162float(row[lane]);
    float x2 = __bfloat162float(row[lane+64]);
    float ss = x1*x1 + x2*x2;
    #pragma unroll
    for (int m = 1; m < 64; m <<= 1) ss += __shfl_xor(ss, m, 64);
    const float rs = rsqrtf(ss*(1.f/128.f) + 1e-6f);
    const float n1 = x1*rs*(1.f + kw[lane]), n2 = x2*rs*(1.f + kw[lane+64]);
    row[lane]    = __float2bfloat16(n1*cw - n2*sw);
    row[lane+64] = __float2bfloat16(n2*cw + n1*sw);
  }
}

// v_raw [b*T+t][kvh*128+d]  ->  Vt [b][kvh][d][T]
__global__ __launch_bounds__(256) void vtrans(const bf16* __restrict__ vraw,
                                              bf16* __restrict__ Vt)
{
  __shared__ bf16 tile[64][65];
  const int t0 = blockIdx.x * 64;
  const int c0 = blockIdx.y * 64;
  const int b  = blockIdx.z;
  const int tx = threadIdx.x & 63;
  const int ty = threadIdx.x >> 6;
  const bf16* src = vraw + (size_t)b * T_ * (NKV_*HD_);
  bf16* dst       = Vt   + (size_t)b * (NKV_*HD_) * T_;
  #pragma unroll
  for (int i = 0; i < 16; ++i) {
    const int r = i*4 + ty;
    tile[r][tx] = src[(size_t)(t0 + r)*(NKV_*HD_) + c0 + tx];
  }
  __syncthreads();
  #pragma unroll
  for (int i = 0; i < 16; ++i) {
    const int r = i*4 + ty;
    dst[(size_t)(c0 + r)*T_ + t0 + tx] = tile[tx][r];
  }
}

// Flash attention v8: GQA-shared K/V, 8 waves = 4 heads x 2 q-halves.
// Double-buffered K/V with 2-phase prefetch (issue next tile's global_load_lds
// BEFORE computing current -> vmcnt(0) at tile end finds loads landed).
// One barrier per tile. P: stride-64, 16B-XOR swizzle (slot ^ (l15&7)) -> fits
// LDS budget at exactly 80 KiB = 2 blocks/CU. exp2-folded softmax.
__global__ __launch_bounds__(512, 4) void attn(
    const bf16* __restrict__ Q, const bf16* __restrict__ Kb,
    const bf16* __restrict__ Vt, bf16* __restrict__ att)
{
  const int id  = blockIdx.x;          // 0..511
  const int s   = 63 - (id >> 3);      // 32-row q slice, heavy-first
  const int kvh = (id >> 1) & 3;       // 0..3
  const int b   = id & 1;              // 0..1
  const int tid = threadIdx.x, lane = tid & 63, w = tid >> 6;  // w 0..7
  const int h   = kvh*4 + (w & 3);     // this wave's q head
  const int l15 = lane & 15;
  const int g   = lane >> 4;           // 0..3
  const int lr4 = g * 4;
  const int swz = l15 & 7;             // K/V read-side swizzle

  const int q0w = s*32 + (w >> 2)*16;  // this wave's 16 q-rows
  const int nt  = (s >> 1) + 1;        // KV tiles of 64

  __shared__ bf16 Ks[2][64*128];       // [kv][d], swizzled 16B slots (16 KiB ea)
  __shared__ bf16 Vs[2][128*64];       // [d][kv], swizzled 16B slots (16 KiB ea)
  __shared__ bf16 Plds[8][16*64];      // wave-private P, 16B-XOR swizzled

  const bf16* Kglob = Kb + (size_t)b*T_*(NKV_*HD_) + kvh*HD_;
  const bf16* Vglob = Vt + (size_t)(b*NKV_ + kvh)*HD_*T_;

  bh8 aQ[4];
  #pragma unroll
  for (int kk = 0; kk < 4; ++kk)
    aQ[kk] = *(const bh8*)&Q[(size_t)(b*T_ + q0w + l15)*(NH_*HD_) + h*HD_ + kk*32 + g*8];

  f32x4 acc[8] = {};
  float mL = -1e30f, lL = 0.f;

  // ---- staging macro-equivalent: 4 gload16 per thread per tile ----
  #define STAGE_KV(buf, kv0s)                                                   \
    {                                                                           \
      _Pragma("unroll")                                                         \
      for (int i = 0; i < 2; ++i) {                                             \
        const int o = i*512 + tid;                                              \
        const int r = o >> 4, sl = o & 15;                                      \
        gload16(Kglob + (size_t)((kv0s) + r)*(NKV_*HD_) + ((sl ^ (r & 7)) << 3),\
                &Ks[buf][o*8]);                                                 \
      }                                                                         \
      _Pragma("unroll")                                                         \
      for (int i = 0; i < 2; ++i) {                                             \
        const int o = i*512 + tid;                                              \
        const int d = o >> 3, sl = o & 7;                                       \
        gload16(Vglob + (size_t)d*T_ + (kv0s) + ((sl ^ (d & 7)) << 3),          \
                &Vs[buf][o*8]);                                                 \
      }                                                                         \
    }

  // prologue: stage tile 0
  STAGE_KV(0, 0);
  asm volatile("s_waitcnt vmcnt(0)" ::: "memory");
  __syncthreads();

  for (int j = 0; j < nt; ++j) {
    const int cur = j & 1;
    const int kv0 = j*64;

    // issue next tile's staging FIRST (lands during this tile's compute)
    if (j + 1 < nt) STAGE_KV(cur ^ 1, kv0 + 64);

    // QK^T (swapped): S[jb] rows = kv(jb*16+lr4+r), cols = q(l15)
    f32x4 S[4] = {};
    #pragma unroll
    for (int jb = 0; jb < 4; ++jb)
      #pragma unroll
      for (int kk = 0; kk < 4; ++kk) {
        const bh8 kf = *(const bh8*)&Ks[cur][(jb*16 + l15)*128 + (((kk*4 + g) ^ swz) << 3)];
        S[jb] = __builtin_amdgcn_mfma_f32_16x16x32_bf16(kf, aQ[kk], S[jb], 0,0,0);
      }

    // in-lane online softmax (exp2-folded): lane owns q-row = q0w + l15
    const bool diag = (j == nt - 1);
    float sv[16];
    float mx = -1e30f;
    #pragma unroll
    for (int jb = 0; jb < 4; ++jb)
      #pragma unroll
      for (int r = 0; r < 4; ++r) {
        float sc = S[jb][r] * SCALE2_;
        if (diag && (kv0 + jb*16 + lr4 + r) > (q0w + l15)) sc = -1e30f;
        sv[jb*4 + r] = sc;
        mx = fmaxf(mx, sc);
      }
    mx = fmaxf(mx, __shfl_xor(mx, 16, 64));
    mx = fmaxf(mx, __shfl_xor(mx, 32, 64));
    const float mn = fmaxf(mL, mx);
    const float al = exp2f(mL - mn);
    mL = mn;
    float sum = 0.f;
    #pragma unroll
    for (int i = 0; i < 16; ++i) { sv[i] = exp2f(sv[i] - mn); sum += sv[i]; }
    sum += __shfl_xor(sum, 16, 64);
    sum += __shfl_xor(sum, 32, 64);
    lL = lL*al + sum;

    // P -> wave-private LDS, stride 64, 16B-slot XOR swizzle by (l15&7).
    // write quad jb: logical slot16 = jb*2 + (g>>1), half = g&1
    bf16* pl = Plds[w];
    #pragma unroll
    for (int jb = 0; jb < 4; ++jb) {
      bf16 pk[4];
      #pragma unroll
      for (int r = 0; r < 4; ++r) pk[r] = __float2bfloat16(sv[jb*4 + r]);
      *(us4*)((char*)pl + l15*128 + ((((jb<<1) | (g>>1)) ^ swz) << 4) + ((g&1) << 3))
          = *(const us4*)pk;
    }

    // rescale acc (rows q = q0w + lr4 + r): al from lane with l15 = lr4+r
    float alr[4];
    #pragma unroll
    for (int r = 0; r < 4; ++r)
      alr[r] = __shfl(al, (lane & 48) | (lr4 + r), 64);
    #pragma unroll
    for (int jd = 0; jd < 8; ++jd)
      #pragma unroll
      for (int r = 0; r < 4; ++r) acc[jd][r] *= alr[r];

    // wave-local ds_write -> ds_read ordering (rule 18)
    asm volatile("s_waitcnt lgkmcnt(0)" ::: "memory");
    __builtin_amdgcn_sched_barrier(0);

    // read A-frags: logical slot16 = g (pa0) / 4+g (pa1), same XOR
    const bh8 pa0 = *(const bh8*)((const char*)pl + l15*128 + (((g    ) ^ swz) << 4));
    const bh8 pa1 = *(const bh8*)((const char*)pl + l15*128 + (((4 + g) ^ swz) << 4));
    #pragma unroll
    for (int jd = 0; jd < 8; ++jd) {
      const bh8 vf0 = *(const bh8*)&Vs[cur][(jd*16 + l15)*64 + (((g    ) ^ swz) << 3)];
      const bh8 vf1 = *(const bh8*)&Vs[cur][(jd*16 + l15)*64 + (((4 + g) ^ swz) << 3)];
      acc[jd] = __builtin_amdgcn_mfma_f32_16x16x32_bf16(pa0, vf0, acc[jd], 0,0,0);
      acc[jd] = __builtin_amdgcn_mfma_f32_16x16x32_bf16(pa1, vf1, acc[jd], 0,0,0);
    }

    // next tile's stage already landed; one barrier flips the buffers
    asm volatile("s_waitcnt vmcnt(0)" ::: "memory");
    __syncthreads();
  }
  #undef STAGE_KV

  // epilogue: bring 1/l into acc row-space and store
  float lar[4];
  #pragma unroll
  for (int r = 0; r < 4; ++r)
    lar[r] = __shfl(lL, (lane & 48) | (lr4 + r), 64);
  #pragma unroll
  for (int r = 0; r < 4; ++r) {
    const float inv = 1.f / lar[r];
    const int row = q0w + lr4 + r;
    bf16* orow = att + ((size_t)(b*T_ + row))*(NH_*HD_) + h*HD_;
    #pragma unroll
    for (int jd = 0; jd < 8; ++jd)
      orow[jd*16 + l15] = __float2bfloat16(acc[jd][r] * inv);
  }
}

extern "C" void kernel_launch(void* const* d_in, const int* in_sizes, int n_in,
                              void* d_out, int out_size, void* d_ws, size_t ws_size,
                              hipStream_t stream) {
  const float* x  = (const float*)d_in[0];
  const float* Wq = (const float*)d_in[1];
  const float* Wk = (const float*)d_in[2];
  const float* Wv = (const float*)d_in[3];
  const float* Wo = (const float*)d_in[4];
  const float* qw = (const float*)d_in[5];
  const float* kw = (const float*)d_in[6];
  float* out = (float*)d_out;

  char* ws = (char*)d_ws;
  bf16* xb   = (bf16*)(ws);                  // 16MB  (-> att later)
  bf16* Wqb  = (bf16*)(ws + (16u<<20));      // 8MB
  bf16* Wkb  = (bf16*)(ws + (24u<<20));      // 2MB
  bf16* Wvb  = (bf16*)(ws + (26u<<20));      // 2MB
  bf16* Wob  = (bf16*)(ws + (28u<<20));      // 8MB
  bf16* kbuf = (bf16*)(ws + (36u<<20));      // 4MB
  bf16* vraw = (bf16*)(ws + (40u<<20));      // 4MB
  bf16* Vt   = (bf16*)(ws + (44u<<20));      // 4MB
  bf16* att  = xb;
  bf16* qbuf = (bf16*)d_out;                 // Q scratch in d_out

  cvt32to16<<<dim3(2048), 256, 0, stream>>>(x,  xb,  M_*H_);
  cvt32to16<<<dim3(1024), 256, 0, stream>>>(Wq, Wqb, NH_*HD_*H_);
  cvt32to16<<<dim3(256),  256, 0, stream>>>(Wk, Wkb, NKV_*HD_*H_);
  cvt32to16<<<dim3(256),  256, 0, stream>>>(Wv, Wvb, NKV_*HD_*H_);
  cvt32to16<<<dim3(1024), 256, 0, stream>>>(Wo, Wob, H_*NH_*HD_);

  gemm_qkv<<<dim3(768), 256, 0, stream>>>(xb, Wqb, Wkb, Wvb, qbuf, kbuf, vraw);
  postproc<<<dim3(M_), 256, 0, stream>>>(qbuf, kbuf, qw, kw);
  vtrans<<<dim3(T_/64, (NKV_*HD_)/64, B_), 256, 0, stream>>>(vraw, Vt);
  attn<<<dim3(512), 512, 0, stream>>>(qbuf, kbuf, Vt, att);
  gemm_o<<<dim3(16, 32), 256, 0, stream>>>(att, Wob, out);
}

// Round 13
// 256.360 us; speedup vs baseline: 1.0018x; 1.0018x over previous
//
#include <hip/hip_runtime.h>
#include <hip/hip_bf16.h>
#include <stdint.h>

#define B_   2
#define T_   2048
#define H_   2048
#define NH_  16
#define NKV_ 4
#define HD_  128
#define M_   (B_*T_)
#define SCALE_  0.08838834764831845f
#define SCALE2_ (0.08838834764831845f * 1.4426950408889634f)   // scale * log2(e)

typedef __hip_bfloat16 bf16;
typedef __attribute__((ext_vector_type(8))) short bh8;
typedef __attribute__((ext_vector_type(4))) float f32x4;
typedef __attribute__((ext_vector_type(4))) unsigned short us4;

__device__ __forceinline__ void gload16(const bf16* g, bf16* l) {
  __builtin_amdgcn_global_load_lds(
      (const __attribute__((address_space(1))) void*)g,
      (__attribute__((address_space(3))) void*)l, 16, 0, 0);
}

__device__ __forceinline__ void cstore(bf16* p, float v)  { *p = __float2bfloat16(v); }
__device__ __forceinline__ void cstore(float* p, float v) { *p = v; }

// fp32 -> bf16 elementwise (n multiple of 8)
__global__ __launch_bounds__(256) void cvt32to16(const float* __restrict__ src,
                                                 bf16* __restrict__ dst, int n)
{
  const int stride = gridDim.x * 256 * 8;
  for (int i = (blockIdx.x * 256 + threadIdx.x) * 8; i < n; i += stride) {
    const float4 a = *(const float4*)(src + i);
    const float4 b = *(const float4*)(src + i + 4);
    bf16 o[8];
    o[0]=__float2bfloat16(a.x); o[1]=__float2bfloat16(a.y);
    o[2]=__float2bfloat16(a.z); o[3]=__float2bfloat16(a.w);
    o[4]=__float2bfloat16(b.x); o[5]=__float2bfloat16(b.y);
    o[6]=__float2bfloat16(b.z); o[7]=__float2bfloat16(b.w);
    *(bh8*)(dst + i) = *(const bh8*)o;
  }
}

// ---------------------------------------------------------------------------
// 256x256 8-phase GEMM (m201-style template): C[m][n] = sum_k A[m][k]*W[n][k].
// 512 threads = 8 waves (2M x 4N), per-wave 128x64 output. BK=64, 2 K-tiles
// per iteration. Static buffers: phases 1-4 read LA[0]/LB[0] (even kt),
// phases 5-8 read LA[1]/LB[1] (odd kt). Stage schedule (iteration j):
//   ph1: LA1.h0<-A(2j+1)  ph2: LA1.h1<-A(2j+1)  ph3: LB0.h0<-B(2j+2)
//   ph4: LB0.h1<-B(2j+2)  ph5: LA0.h0<-A(2j+2)  ph6: LA0.h1<-A(2j+2)
//   ph7: LB1.h0<-B(2j+3)  ph8: LB1.h1<-B(2j+3)
// vmcnt(4) at ph4/ph8 drains exactly the half-tiles the next phase-group
// reads (per-thread in-flight 12 -> 4, never 0). XOR slot swizzle (rule 21):
// LDS linear dest, source slot pre-swizzled with (row&7), reads apply same.
// N-split decode lets one kernel serve fused QKV (N=3072) and O-proj.
// ---------------------------------------------------------------------------
template<typename OutT>
__global__ __launch_bounds__(512, 2) void gemm256(
    const bf16* __restrict__ A,
    const bf16* __restrict__ W0, const bf16* __restrict__ W1, const bf16* __restrict__ W2,
    OutT* __restrict__ C0, OutT* __restrict__ C1, OutT* __restrict__ C2,
    int K, int nbN, int t1, int t2, int N0)
{
  const int bid = blockIdx.x;
  const int mb = bid / nbN, nb = bid % nbN;
  const int m0 = mb * 256;
  const int n0g = nb * 256;
  const bf16* W; OutT* C; int Nloc, nc0;
  if (nb < t1)      { W = W0 + (size_t)n0g*K;            C = C0; Nloc = N0;  nc0 = n0g; }
  else if (nb < t2) { W = W1 + (size_t)(n0g - t1*256)*K; C = C1; Nloc = 512; nc0 = n0g - t1*256; }
  else              { W = W2 + (size_t)(n0g - t2*256)*K; C = C2; Nloc = 512; nc0 = n0g - t2*256; }
  const bf16* Ag = A + (size_t)m0 * K;

  const int tid = threadIdx.x, lane = tid & 63, w = tid >> 6;
  const int wm = w >> 2, wn = w & 3;          // 2M x 4N waves
  const int l15 = lane & 15, g = lane >> 4;
  const int swz = l15 & 7;

  __shared__ bf16 LA[2][256*64];   // 2 x 32 KiB
  __shared__ bf16 LB[2][256*64];   // 2 x 32 KiB  (total 128 KiB)

  f32x4 acc[8][4] = {};
  bh8 bfr[4][2];

  const int ktmask = (K >> 6) - 1;
  const int niter  = K >> 7;

  // stage one half-tile (128 rows x 64 cols): 2 gloads/thread, linear dest,
  // source slot pre-swizzled by (row&7)
  #define STG(DST, SRC, KT, HALF)                                                   \
    { _Pragma("unroll")                                                             \
      for (int i_ = 0; i_ < 2; ++i_) {                                              \
        const int o_ = i_*512 + tid; const int r_ = o_ >> 3; const int sl_ = o_ & 7;\
        gload16((SRC) + (size_t)((HALF)*128 + r_)*K + (KT)*64 + ((sl_ ^ (r_ & 7)) << 3), \
                (DST) + (HALF)*8192 + o_*8);                                        \
      } }

  // prologue: kt0 A+B -> buf0, kt1 B -> buf1 (B last so vmcnt(4) keeps it in flight)
  STG(LA[0], Ag, 0, 0); STG(LA[0], Ag, 0, 1);
  STG(LB[0], W,  0, 0); STG(LB[0], W,  0, 1);
  STG(LB[1], W,  1, 0); STG(LB[1], W,  1, 1);
  asm volatile("s_waitcnt vmcnt(4)" ::: "memory");
  __builtin_amdgcn_s_barrier();

  #define PHASE(MI0, RBUF, DOB, SDST, SSRC, SKT, SHALF, CHK)                        \
    {                                                                               \
      if (DOB) {                                                                    \
        _Pragma("unroll") for (int nj=0;nj<4;++nj)                                  \
        _Pragma("unroll") for (int ks=0;ks<2;++ks)                                  \
          bfr[nj][ks] = *(const bh8*)&LB[RBUF][(wn*64+nj*16+l15)*64 + (((ks*4+g)^swz)<<3)]; \
      }                                                                             \
      bh8 af_[2][2];                                                                \
      _Pragma("unroll") for (int mi=0;mi<2;++mi)                                    \
      _Pragma("unroll") for (int ks=0;ks<2;++ks)                                    \
        af_[mi][ks] = *(const bh8*)&LA[RBUF][(wm*128+((MI0)+mi)*16+l15)*64 + (((ks*4+g)^swz)<<3)]; \
      STG(SDST, SSRC, SKT, SHALF);                                                  \
      __builtin_amdgcn_s_barrier();                                                 \
      asm volatile("s_waitcnt lgkmcnt(0)" ::: "memory");                            \
      __builtin_amdgcn_sched_barrier(0);                                            \
      __builtin_amdgcn_s_setprio(1);                                                \
      _Pragma("unroll") for (int mi=0;mi<2;++mi)                                    \
      _Pragma("unroll") for (int nj=0;nj<4;++nj) {                                  \
        acc[(MI0)+mi][nj] = __builtin_amdgcn_mfma_f32_16x16x32_bf16(af_[mi][0], bfr[nj][0], acc[(MI0)+mi][nj],0,0,0); \
        acc[(MI0)+mi][nj] = __builtin_amdgcn_mfma_f32_16x16x32_bf16(af_[mi][1], bfr[nj][1], acc[(MI0)+mi][nj],0,0,0); \
      }                                                                             \
      __builtin_amdgcn_s_setprio(0);                                                \
      if (CHK) { asm volatile("s_waitcnt vmcnt(4)" ::: "memory"); }                 \
      __builtin_amdgcn_s_barrier();                                                 \
    }

  for (int j = 0; j < niter; ++j) {
    const int kta = 2*j + 1;                 // always < K/64
    const int ktb = (2*j + 2) & ktmask;      // wraps harmlessly on last iter
    const int ktc = (2*j + 3) & ktmask;
    PHASE(0, 0, true , LA[1], Ag, kta, 0, false)
    PHASE(2, 0, false, LA[1], Ag, kta, 1, false)
    PHASE(4, 0, false, LB[0], W,  ktb, 0, false)
    PHASE(6, 0, false, LB[0], W,  ktb, 1, true )
    PHASE(0, 1, true , LA[0], Ag, ktb, 0, false)
    PHASE(2, 1, false, LA[0], Ag, ktb, 1, false)
    PHASE(4, 1, false, LB[1], W,  ktc, 0, false)
    PHASE(6, 1, false, LB[1], W,  ktc, 1, true )
  }
  #undef PHASE
  #undef STG

  // epilogue
  #pragma unroll
  for (int mi = 0; mi < 8; ++mi)
    #pragma unroll
    for (int r = 0; r < 4; ++r) {
      const int row = m0 + wm*128 + mi*16 + (lane>>4)*4 + r;
      #pragma unroll
      for (int nj = 0; nj < 4; ++nj) {
        const int col = nc0 + wn*64 + nj*16 + l15;
        cstore(&C[(size_t)row*Nloc + col], acc[mi][nj][r]);
      }
    }
}

// Per (b,t): RMSNorm(HD) + RoPE IN PLACE. Lane l owns d=l and d=l+64.
__global__ __launch_bounds__(256) void postproc(
    bf16* __restrict__ q, bf16* __restrict__ k,
    const float* __restrict__ qw, const float* __restrict__ kw)
{
  const int blk  = blockIdx.x;
  const int t    = blk & (T_-1);
  const int lane = threadIdx.x & 63;
  const int w    = threadIdx.x >> 6;

  const float inv = expf(-(float)lane * (9.210340371976184f / 64.f));
  const float ang = (float)t * inv;
  const float cw = cosf(ang), sw = sinf(ang);

  #pragma unroll
  for (int hi = 0; hi < 4; ++hi) {
    const int h = w + hi*4;
    bf16* row = q + (size_t)blk*(NH_*HD_) + h*HD_;
    float x1 = __bfloat162float(row[lane]);
    float x2 = __bfloat162float(row[lane+64]);
    float ss = x1*x1 + x2*x2;
    #pragma unroll
    for (int m = 1; m < 64; m <<= 1) ss += __shfl_xor(ss, m, 64);
    const float rs = rsqrtf(ss*(1.f/128.f) + 1e-6f);
    const float n1 = x1*rs*(1.f + qw[lane]), n2 = x2*rs*(1.f + qw[lane+64]);
    row[lane]    = __float2bfloat16(n1*cw - n2*sw);
    row[lane+64] = __float2bfloat16(n2*cw + n1*sw);
  }
  {
    bf16* row = k + (size_t)blk*(NKV_*HD_) + w*HD_;
    float x1 = __bfloat162float(row[lane]);
    float x2 = __bfloat162float(row[lane+64]);
    float ss = x1*x1 + x2*x2;
    #pragma unroll
    for (int m = 1; m < 64; m <<= 1) ss += __shfl_xor(ss, m, 64);
    const float rs = rsqrtf(ss*(1.f/128.f) + 1e-6f);
    const float n1 = x1*rs*(1.f + kw[lane]), n2 = x2*rs*(1.f + kw[lane+64]);
    row[lane]    = __float2bfloat16(n1*cw - n2*sw);
    row[lane+64] = __float2bfloat16(n2*cw + n1*sw);
  }
}

// v_raw [b*T+t][kvh*128+d]  ->  Vt [b][kvh][d][T]
__global__ __launch_bounds__(256) void vtrans(const bf16* __restrict__ vraw,
                                              bf16* __restrict__ Vt)
{
  __shared__ bf16 tile[64][65];
  const int t0 = blockIdx.x * 64;
  const int c0 = blockIdx.y * 64;
  const int b  = blockIdx.z;
  const int tx = threadIdx.x & 63;
  const int ty = threadIdx.x >> 6;
  const bf16* src = vraw + (size_t)b * T_ * (NKV_*HD_);
  bf16* dst       = Vt   + (size_t)b * (NKV_*HD_) * T_;
  #pragma unroll
  for (int i = 0; i < 16; ++i) {
    const int r = i*4 + ty;
    tile[r][tx] = src[(size_t)(t0 + r)*(NKV_*HD_) + c0 + tx];
  }
  __syncthreads();
  #pragma unroll
  for (int i = 0; i < 16; ++i) {
    const int r = i*4 + ty;
    dst[(size_t)(c0 + r)*T_ + t0 + tx] = tile[tx][r];
  }
}

// Flash attention v8 (unchanged from round 12): GQA-shared K/V, 8 waves,
// double-buffered K/V with prefetch-before-compute, one barrier per tile,
// exp2 softmax, 80 KiB LDS -> 2 blocks/CU.
__global__ __launch_bounds__(512, 4) void attn(
    const bf16* __restrict__ Q, const bf16* __restrict__ Kb,
    const bf16* __restrict__ Vt, bf16* __restrict__ att)
{
  const int id  = blockIdx.x;          // 0..511
  const int s   = 63 - (id >> 3);      // 32-row q slice, heavy-first
  const int kvh = (id >> 1) & 3;       // 0..3
  const int b   = id & 1;              // 0..1
  const int tid = threadIdx.x, lane = tid & 63, w = tid >> 6;  // w 0..7
  const int h   = kvh*4 + (w & 3);     // this wave's q head
  const int l15 = lane & 15;
  const int g   = lane >> 4;           // 0..3
  const int lr4 = g * 4;
  const int swz = l15 & 7;             // K/V read-side swizzle

  const int q0w = s*32 + (w >> 2)*16;  // this wave's 16 q-rows
  const int nt  = (s >> 1) + 1;        // KV tiles of 64

  __shared__ bf16 Ks[2][64*128];
  __shared__ bf16 Vs[2][128*64];
  __shared__ bf16 Plds[8][16*64];

  const bf16* Kglob = Kb + (size_t)b*T_*(NKV_*HD_) + kvh*HD_;
  const bf16* Vglob = Vt + (size_t)(b*NKV_ + kvh)*HD_*T_;

  bh8 aQ[4];
  #pragma unroll
  for (int kk = 0; kk < 4; ++kk)
    aQ[kk] = *(const bh8*)&Q[(size_t)(b*T_ + q0w + l15)*(NH_*HD_) + h*HD_ + kk*32 + g*8];

  f32x4 acc[8] = {};
  float mL = -1e30f, lL = 0.f;

  #define STAGE_KV(buf, kv0s)                                                   \
    {                                                                           \
      _Pragma("unroll")                                                         \
      for (int i = 0; i < 2; ++i) {                                             \
        const int o = i*512 + tid;                                              \
        const int r = o >> 4, sl = o & 15;                                      \
        gload16(Kglob + (size_t)((kv0s) + r)*(NKV_*HD_) + ((sl ^ (r & 7)) << 3),\
                &Ks[buf][o*8]);                                                 \
      }                                                                         \
      _Pragma("unroll")                                                         \
      for (int i = 0; i < 2; ++i) {                                             \
        const int o = i*512 + tid;                                              \
        const int d = o >> 3, sl = o & 7;                                       \
        gload16(Vglob + (size_t)d*T_ + (kv0s) + ((sl ^ (d & 7)) << 3),          \
                &Vs[buf][o*8]);                                                 \
      }                                                                         \
    }

  STAGE_KV(0, 0);
  asm volatile("s_waitcnt vmcnt(0)" ::: "memory");
  __syncthreads();

  for (int j = 0; j < nt; ++j) {
    const int cur = j & 1;
    const int kv0 = j*64;

    if (j + 1 < nt) STAGE_KV(cur ^ 1, kv0 + 64);

    f32x4 S[4] = {};
    #pragma unroll
    for (int jb = 0; jb < 4; ++jb)
      #pragma unroll
      for (int kk = 0; kk < 4; ++kk) {
        const bh8 kf = *(const bh8*)&Ks[cur][(jb*16 + l15)*128 + (((kk*4 + g) ^ swz) << 3)];
        S[jb] = __builtin_amdgcn_mfma_f32_16x16x32_bf16(kf, aQ[kk], S[jb], 0,0,0);
      }

    const bool diag = (j == nt - 1);
    float sv[16];
    float mx = -1e30f;
    #pragma unroll
    for (int jb = 0; jb < 4; ++jb)
      #pragma unroll
      for (int r = 0; r < 4; ++r) {
        float sc = S[jb][r] * SCALE2_;
        if (diag && (kv0 + jb*16 + lr4 + r) > (q0w + l15)) sc = -1e30f;
        sv[jb*4 + r] = sc;
        mx = fmaxf(mx, sc);
      }
    mx = fmaxf(mx, __shfl_xor(mx, 16, 64));
    mx = fmaxf(mx, __shfl_xor(mx, 32, 64));
    const float mn = fmaxf(mL, mx);
    const float al = exp2f(mL - mn);
    mL = mn;
    float sum = 0.f;
    #pragma unroll
    for (int i = 0; i < 16; ++i) { sv[i] = exp2f(sv[i] - mn); sum += sv[i]; }
    sum += __shfl_xor(sum, 16, 64);
    sum += __shfl_xor(sum, 32, 64);
    lL = lL*al + sum;

    bf16* pl = Plds[w];
    #pragma unroll
    for (int jb = 0; jb < 4; ++jb) {
      bf16 pk[4];
      #pragma unroll
      for (int r = 0; r < 4; ++r) pk[r] = __float2bfloat16(sv[jb*4 + r]);
      *(us4*)((char*)pl + l15*128 + ((((jb<<1) | (g>>1)) ^ swz) << 4) + ((g&1) << 3))
          = *(const us4*)pk;
    }

    float alr[4];
    #pragma unroll
    for (int r = 0; r < 4; ++r)
      alr[r] = __shfl(al, (lane & 48) | (lr4 + r), 64);
    #pragma unroll
    for (int jd = 0; jd < 8; ++jd)
      #pragma unroll
      for (int r = 0; r < 4; ++r) acc[jd][r] *= alr[r];

    asm volatile("s_waitcnt lgkmcnt(0)" ::: "memory");
    __builtin_amdgcn_sched_barrier(0);

    const bh8 pa0 = *(const bh8*)((const char*)pl + l15*128 + (((g    ) ^ swz) << 4));
    const bh8 pa1 = *(const bh8*)((const char*)pl + l15*128 + (((4 + g) ^ swz) << 4));
    #pragma unroll
    for (int jd = 0; jd < 8; ++jd) {
      const bh8 vf0 = *(const bh8*)&Vs[cur][(jd*16 + l15)*64 + (((g    ) ^ swz) << 3)];
      const bh8 vf1 = *(const bh8*)&Vs[cur][(jd*16 + l15)*64 + (((4 + g) ^ swz) << 3)];
      acc[jd] = __builtin_amdgcn_mfma_f32_16x16x32_bf16(pa0, vf0, acc[jd], 0,0,0);
      acc[jd] = __builtin_amdgcn_mfma_f32_16x16x32_bf16(pa1, vf1, acc[jd], 0,0,0);
    }

    asm volatile("s_waitcnt vmcnt(0)" ::: "memory");
    __syncthreads();
  }
  #undef STAGE_KV

  float lar[4];
  #pragma unroll
  for (int r = 0; r < 4; ++r)
    lar[r] = __shfl(lL, (lane & 48) | (lr4 + r), 64);
  #pragma unroll
  for (int r = 0; r < 4; ++r) {
    const float inv = 1.f / lar[r];
    const int row = q0w + lr4 + r;
    bf16* orow = att + ((size_t)(b*T_ + row))*(NH_*HD_) + h*HD_;
    #pragma unroll
    for (int jd = 0; jd < 8; ++jd)
      orow[jd*16 + l15] = __float2bfloat16(acc[jd][r] * inv);
  }
}

extern "C" void kernel_launch(void* const* d_in, const int* in_sizes, int n_in,
                              void* d_out, int out_size, void* d_ws, size_t ws_size,
                              hipStream_t stream) {
  const float* x  = (const float*)d_in[0];
  const float* Wq = (const float*)d_in[1];
  const float* Wk = (const float*)d_in[2];
  const float* Wv = (const float*)d_in[3];
  const float* Wo = (const float*)d_in[4];
  const float* qw = (const float*)d_in[5];
  const float* kw = (const float*)d_in[6];
  float* out = (float*)d_out;

  char* ws = (char*)d_ws;
  bf16* xb   = (bf16*)(ws);                  // 16MB  (-> att later)
  bf16* Wqb  = (bf16*)(ws + (16u<<20));      // 8MB
  bf16* Wkb  = (bf16*)(ws + (24u<<20));      // 2MB
  bf16* Wvb  = (bf16*)(ws + (26u<<20));      // 2MB
  bf16* Wob  = (bf16*)(ws + (28u<<20));      // 8MB
  bf16* kbuf = (bf16*)(ws + (36u<<20));      // 4MB
  bf16* vraw = (bf16*)(ws + (40u<<20));      // 4MB
  bf16* Vt   = (bf16*)(ws + (44u<<20));      // 4MB
  bf16* att  = xb;
  bf16* qbuf = (bf16*)d_out;                 // Q scratch in d_out

  cvt32to16<<<dim3(2048), 256, 0, stream>>>(x,  xb,  M_*H_);
  cvt32to16<<<dim3(1024), 256, 0, stream>>>(Wq, Wqb, NH_*HD_*H_);
  cvt32to16<<<dim3(256),  256, 0, stream>>>(Wk, Wkb, NKV_*HD_*H_);
  cvt32to16<<<dim3(256),  256, 0, stream>>>(Wv, Wvb, NKV_*HD_*H_);
  cvt32to16<<<dim3(1024), 256, 0, stream>>>(Wo, Wob, H_*NH_*HD_);

  // fused QKV: N = 2048(Q) + 512(K) + 512(V) = 3072 -> 16m x 12n = 192 blocks
  gemm256<bf16><<<dim3(192), 512, 0, stream>>>(xb, Wqb, Wkb, Wvb,
                                               qbuf, kbuf, vraw,
                                               2048, 12, 8, 10, 2048);
  postproc<<<dim3(M_), 256, 0, stream>>>(qbuf, kbuf, qw, kw);
  vtrans<<<dim3(T_/64, (NKV_*HD_)/64, B_), 256, 0, stream>>>(vraw, Vt);
  attn<<<dim3(512), 512, 0, stream>>>(qbuf, kbuf, Vt, att);
  // O-proj: 16m x 8n = 128 blocks, fp32 out
  gemm256<float><<<dim3(128), 512, 0, stream>>>(att, Wob, Wob, Wob,
                                                out, out, out,
                                                2048, 8, 99, 99, 2048);
}

// Round 15
// 245.935 us; speedup vs baseline: 1.0442x; 1.0424x over previous
//
#include <hip/hip_runtime.h>
#include <hip/hip_bf16.h>
#include <stdint.h>

#define B_   2
#define T_   2048
#define H_   2048
#define NH_  16
#define NKV_ 4
#define HD_  128
#define M_   (B_*T_)
#define SCALE_  0.08838834764831845f
#define SCALE2_ (0.08838834764831845f * 1.4426950408889634f)   // scale * log2(e)

typedef __hip_bfloat16 bf16;
typedef __attribute__((ext_vector_type(8))) short bh8;
typedef __attribute__((ext_vector_type(4))) float f32x4;
typedef __attribute__((ext_vector_type(4))) unsigned short us4;

__device__ __forceinline__ void gload16(const bf16* g, bf16* l) {
  __builtin_amdgcn_global_load_lds(
      (const __attribute__((address_space(1))) void*)g,
      (__attribute__((address_space(3))) void*)l, 16, 0, 0);
}

__device__ __forceinline__ void cstore(bf16* p, float v)  { *p = __float2bfloat16(v); }
__device__ __forceinline__ void cstore(float* p, float v) { *p = v; }

// fp32 -> bf16 elementwise (n multiple of 8)
__global__ __launch_bounds__(256) void cvt32to16(const float* __restrict__ src,
                                                 bf16* __restrict__ dst, int n)
{
  const int stride = gridDim.x * 256 * 8;
  for (int i = (blockIdx.x * 256 + threadIdx.x) * 8; i < n; i += stride) {
    const float4 a = *(const float4*)(src + i);
    const float4 b = *(const float4*)(src + i + 4);
    bf16 o[8];
    o[0]=__float2bfloat16(a.x); o[1]=__float2bfloat16(a.y);
    o[2]=__float2bfloat16(a.z); o[3]=__float2bfloat16(a.w);
    o[4]=__float2bfloat16(b.x); o[5]=__float2bfloat16(b.y);
    o[6]=__float2bfloat16(b.z); o[7]=__float2bfloat16(b.w);
    *(bh8*)(dst + i) = *(const bh8*)o;
  }
}

// ---------------------------------------------------------------------------
// 256x256 8-phase GEMM (unchanged from round 13).
// ---------------------------------------------------------------------------
template<typename OutT>
__global__ __launch_bounds__(512, 2) void gemm256(
    const bf16* __restrict__ A,
    const bf16* __restrict__ W0, const bf16* __restrict__ W1, const bf16* __restrict__ W2,
    OutT* __restrict__ C0, OutT* __restrict__ C1, OutT* __restrict__ C2,
    int K, int nbN, int t1, int t2, int N0)
{
  const int bid = blockIdx.x;
  const int mb = bid / nbN, nb = bid % nbN;
  const int m0 = mb * 256;
  const int n0g = nb * 256;
  const bf16* W; OutT* C; int Nloc, nc0;
  if (nb < t1)      { W = W0 + (size_t)n0g*K;            C = C0; Nloc = N0;  nc0 = n0g; }
  else if (nb < t2) { W = W1 + (size_t)(n0g - t1*256)*K; C = C1; Nloc = 512; nc0 = n0g - t1*256; }
  else              { W = W2 + (size_t)(n0g - t2*256)*K; C = C2; Nloc = 512; nc0 = n0g - t2*256; }
  const bf16* Ag = A + (size_t)m0 * K;

  const int tid = threadIdx.x, lane = tid & 63, w = tid >> 6;
  const int wm = w >> 2, wn = w & 3;
  const int l15 = lane & 15, g = lane >> 4;
  const int swz = l15 & 7;

  __shared__ bf16 LA[2][256*64];
  __shared__ bf16 LB[2][256*64];

  f32x4 acc[8][4] = {};
  bh8 bfr[4][2];

  const int ktmask = (K >> 6) - 1;
  const int niter  = K >> 7;

  #define STG(DST, SRC, KT, HALF)                                                   \
    { _Pragma("unroll")                                                             \
      for (int i_ = 0; i_ < 2; ++i_) {                                              \
        const int o_ = i_*512 + tid; const int r_ = o_ >> 3; const int sl_ = o_ & 7;\
        gload16((SRC) + (size_t)((HALF)*128 + r_)*K + (KT)*64 + ((sl_ ^ (r_ & 7)) << 3), \
                (DST) + (HALF)*8192 + o_*8);                                        \
      } }

  STG(LA[0], Ag, 0, 0); STG(LA[0], Ag, 0, 1);
  STG(LB[0], W,  0, 0); STG(LB[0], W,  0, 1);
  STG(LB[1], W,  1, 0); STG(LB[1], W,  1, 1);
  asm volatile("s_waitcnt vmcnt(4)" ::: "memory");
  __builtin_amdgcn_s_barrier();

  #define PHASE(MI0, RBUF, DOB, SDST, SSRC, SKT, SHALF, CHK)                        \
    {                                                                               \
      if (DOB) {                                                                    \
        _Pragma("unroll") for (int nj=0;nj<4;++nj)                                  \
        _Pragma("unroll") for (int ks=0;ks<2;++ks)                                  \
          bfr[nj][ks] = *(const bh8*)&LB[RBUF][(wn*64+nj*16+l15)*64 + (((ks*4+g)^swz)<<3)]; \
      }                                                                             \
      bh8 af_[2][2];                                                                \
      _Pragma("unroll") for (int mi=0;mi<2;++mi)                                    \
      _Pragma("unroll") for (int ks=0;ks<2;++ks)                                    \
        af_[mi][ks] = *(const bh8*)&LA[RBUF][(wm*128+((MI0)+mi)*16+l15)*64 + (((ks*4+g)^swz)<<3)]; \
      STG(SDST, SSRC, SKT, SHALF);                                                  \
      __builtin_amdgcn_s_barrier();                                                 \
      asm volatile("s_waitcnt lgkmcnt(0)" ::: "memory");                            \
      __builtin_amdgcn_sched_barrier(0);                                            \
      __builtin_amdgcn_s_setprio(1);                                                \
      _Pragma("unroll") for (int mi=0;mi<2;++mi)                                    \
      _Pragma("unroll") for (int nj=0;nj<4;++nj) {                                  \
        acc[(MI0)+mi][nj] = __builtin_amdgcn_mfma_f32_16x16x32_bf16(af_[mi][0], bfr[nj][0], acc[(MI0)+mi][nj],0,0,0); \
        acc[(MI0)+mi][nj] = __builtin_amdgcn_mfma_f32_16x16x32_bf16(af_[mi][1], bfr[nj][1], acc[(MI0)+mi][nj],0,0,0); \
      }                                                                             \
      __builtin_amdgcn_s_setprio(0);                                                \
      if (CHK) { asm volatile("s_waitcnt vmcnt(4)" ::: "memory"); }                 \
      __builtin_amdgcn_s_barrier();                                                 \
    }

  for (int j = 0; j < niter; ++j) {
    const int kta = 2*j + 1;
    const int ktb = (2*j + 2) & ktmask;
    const int ktc = (2*j + 3) & ktmask;
    PHASE(0, 0, true , LA[1], Ag, kta, 0, false)
    PHASE(2, 0, false, LA[1], Ag, kta, 1, false)
    PHASE(4, 0, false, LB[0], W,  ktb, 0, false)
    PHASE(6, 0, false, LB[0], W,  ktb, 1, true )
    PHASE(0, 1, true , LA[0], Ag, ktb, 0, false)
    PHASE(2, 1, false, LA[0], Ag, ktb, 1, false)
    PHASE(4, 1, false, LB[1], W,  ktc, 0, false)
    PHASE(6, 1, false, LB[1], W,  ktc, 1, true )
  }
  #undef PHASE
  #undef STG

  #pragma unroll
  for (int mi = 0; mi < 8; ++mi)
    #pragma unroll
    for (int r = 0; r < 4; ++r) {
      const int row = m0 + wm*128 + mi*16 + (lane>>4)*4 + r;
      #pragma unroll
      for (int nj = 0; nj < 4; ++nj) {
        const int col = nc0 + wn*64 + nj*16 + l15;
        cstore(&C[(size_t)row*Nloc + col], acc[mi][nj][r]);
      }
    }
}

// Per (b,t): RMSNorm(HD) + RoPE IN PLACE. Lane l owns d=l and d=l+64.
// Q additionally pre-multiplied by SCALE2_ (attn softmax uses raw exp2).
__global__ __launch_bounds__(256) void postproc(
    bf16* __restrict__ q, bf16* __restrict__ k,
    const float* __restrict__ qw, const float* __restrict__ kw)
{
  const int blk  = blockIdx.x;
  const int t    = blk & (T_-1);
  const int lane = threadIdx.x & 63;
  const int w    = threadIdx.x >> 6;

  const float inv = expf(-(float)lane * (9.210340371976184f / 64.f));
  const float ang = (float)t * inv;
  const float cw = cosf(ang), sw = sinf(ang);

  #pragma unroll
  for (int hi = 0; hi < 4; ++hi) {
    const int h = w + hi*4;
    bf16* row = q + (size_t)blk*(NH_*HD_) + h*HD_;
    float x1 = __bfloat162float(row[lane]);
    float x2 = __bfloat162float(row[lane+64]);
    float ss = x1*x1 + x2*x2;
    #pragma unroll
    for (int m = 1; m < 64; m <<= 1) ss += __shfl_xor(ss, m, 64);
    const float rs = rsqrtf(ss*(1.f/128.f) + 1e-6f);
    const float n1 = x1*rs*(1.f + qw[lane]), n2 = x2*rs*(1.f + qw[lane+64]);
    row[lane]    = __float2bfloat16((n1*cw - n2*sw) * SCALE2_);
    row[lane+64] = __float2bfloat16((n2*cw + n1*sw) * SCALE2_);
  }
  {
    bf16* row = k + (size_t)blk*(NKV_*HD_) + w*HD_;
    float x1 = __bfloat162float(row[lane]);
    float x2 = __bfloat162float(row[lane+64]);
    float ss = x1*x1 + x2*x2;
    #pragma unroll
    for (int m = 1; m < 64; m <<= 1) ss += __shfl_xor(ss, m, 64);
    const float rs = rsqrtf(ss*(1.f/128.f) + 1e-6f);
    const float n1 = x1*rs*(1.f + kw[lane]), n2 = x2*rs*(1.f + kw[lane+64]);
    row[lane]    = __float2bfloat16(n1*cw - n2*sw);
    row[lane+64] = __float2bfloat16(n2*cw + n1*sw);
  }
}

// v_raw [b*T+t][kvh*128+d]  ->  Vt [b][kvh][d][T]
__global__ __launch_bounds__(256) void vtrans(const bf16* __restrict__ vraw,
                                              bf16* __restrict__ Vt)
{
  __shared__ bf16 tile[64][65];
  const int t0 = blockIdx.x * 64;
  const int c0 = blockIdx.y * 64;
  const int b  = blockIdx.z;
  const int tx = threadIdx.x & 63;
  const int ty = threadIdx.x >> 6;
  const bf16* src = vraw + (size_t)b * T_ * (NKV_*HD_);
  bf16* dst       = Vt   + (size_t)b * (NKV_*HD_) * T_;
  #pragma unroll
  for (int i = 0; i < 16; ++i) {
    const int r = i*4 + ty;
    tile[r][tx] = src[(size_t)(t0 + r)*(NKV_*HD_) + c0 + tx];
  }
  __syncthreads();
  #pragma unroll
  for (int i = 0; i < 16; ++i) {
    const int r = i*4 + ty;
    dst[(size_t)(c0 + r)*T_ + t0 + tx] = tile[tx][r];
  }
}

// Flash attention v9: FIXED-SHIFT softmax. RMSNorm bounds |q.k*scale*log2e|
// <= 16.4, so exp2 never overflows -> p = exp2(s) directly (shift-invariant,
// mathematically exact). No running max, no acc rescale, no per-tile
// cross-lane reductions; l is a per-lane partial summed once in the epilogue.
// Staging/buffers/barriers identical to v8.
__global__ __launch_bounds__(512, 4) void attn(
    const bf16* __restrict__ Q, const bf16* __restrict__ Kb,
    const bf16* __restrict__ Vt, bf16* __restrict__ att)
{
  const int id  = blockIdx.x;          // 0..511
  const int s   = 63 - (id >> 3);      // 32-row q slice, heavy-first
  const int kvh = (id >> 1) & 3;       // 0..3
  const int b   = id & 1;              // 0..1
  const int tid = threadIdx.x, lane = tid & 63, w = tid >> 6;  // w 0..7
  const int h   = kvh*4 + (w & 3);     // this wave's q head
  const int l15 = lane & 15;
  const int g   = lane >> 4;           // 0..3
  const int lr4 = g * 4;
  const int swz = l15 & 7;             // K/V read-side swizzle

  const int q0w = s*32 + (w >> 2)*16;  // this wave's 16 q-rows
  const int nt  = (s >> 1) + 1;        // KV tiles of 64

  __shared__ bf16 Ks[2][64*128];
  __shared__ bf16 Vs[2][128*64];
  __shared__ bf16 Plds[8][16*64];

  const bf16* Kglob = Kb + (size_t)b*T_*(NKV_*HD_) + kvh*HD_;
  const bf16* Vglob = Vt + (size_t)(b*NKV_ + kvh)*HD_*T_;

  bh8 aQ[4];
  #pragma unroll
  for (int kk = 0; kk < 4; ++kk)
    aQ[kk] = *(const bh8*)&Q[(size_t)(b*T_ + q0w + l15)*(NH_*HD_) + h*HD_ + kk*32 + g*8];

  f32x4 acc[8] = {};
  float lL = 0.f;                      // per-lane partial sum of p

  #define STAGE_KV(buf, kv0s)                                                   \
    {                                                                           \
      _Pragma("unroll")                                                         \
      for (int i = 0; i < 2; ++i) {                                             \
        const int o = i*512 + tid;                                              \
        const int r = o >> 4, sl = o & 15;                                      \
        gload16(Kglob + (size_t)((kv0s) + r)*(NKV_*HD_) + ((sl ^ (r & 7)) << 3),\
                &Ks[buf][o*8]);                                                 \
      }                                                                         \
      _Pragma("unroll")                                                         \
      for (int i = 0; i < 2; ++i) {                                             \
        const int o = i*512 + tid;                                              \
        const int d = o >> 3, sl = o & 7;                                       \
        gload16(Vglob + (size_t)d*T_ + (kv0s) + ((sl ^ (d & 7)) << 3),          \
                &Vs[buf][o*8]);                                                 \
      }                                                                         \
    }

  STAGE_KV(0, 0);
  asm volatile("s_waitcnt vmcnt(0)" ::: "memory");
  __syncthreads();

  for (int j = 0; j < nt; ++j) {
    const int cur = j & 1;
    const int kv0 = j*64;

    if (j + 1 < nt) STAGE_KV(cur ^ 1, kv0 + 64);

    // QK^T (swapped): S[jb] rows = kv(jb*16+lr4+r), cols = q(l15).
    // Q pre-scaled by scale*log2e in postproc.
    f32x4 S[4] = {};
    #pragma unroll
    for (int jb = 0; jb < 4; ++jb)
      #pragma unroll
      for (int kk = 0; kk < 4; ++kk) {
        const bh8 kf = *(const bh8*)&Ks[cur][(jb*16 + l15)*128 + (((kk*4 + g) ^ swz) << 3)];
        S[jb] = __builtin_amdgcn_mfma_f32_16x16x32_bf16(kf, aQ[kk], S[jb], 0,0,0);
      }

    // fixed-shift softmax: p = exp2(s); masked -> 0
    const bool diag = (j == nt - 1);
    float sv[16];
    float sum = 0.f;
    #pragma unroll
    for (int jb = 0; jb < 4; ++jb)
      #pragma unroll
      for (int r = 0; r < 4; ++r) {
        float sc = S[jb][r];
        if (diag && (kv0 + jb*16 + lr4 + r) > (q0w + l15)) sc = -1e30f;
        const float p = exp2f(sc);
        sv[jb*4 + r] = p;
        sum += p;
      }
    lL += sum;

    // P -> wave-private LDS, stride 64, 16B-slot XOR swizzle by (l15&7)
    bf16* pl = Plds[w];
    #pragma unroll
    for (int jb = 0; jb < 4; ++jb) {
      bf16 pk[4];
      #pragma unroll
      for (int r = 0; r < 4; ++r) pk[r] = __float2bfloat16(sv[jb*4 + r]);
      *(us4*)((char*)pl + l15*128 + ((((jb<<1) | (g>>1)) ^ swz) << 4) + ((g&1) << 3))
          = *(const us4*)pk;
    }

    // wave-local ds_write -> ds_read ordering (rule 18)
    asm volatile("s_waitcnt lgkmcnt(0)" ::: "memory");
    __builtin_amdgcn_sched_barrier(0);

    const bh8 pa0 = *(const bh8*)((const char*)pl + l15*128 + (((g    ) ^ swz) << 4));
    const bh8 pa1 = *(const bh8*)((const char*)pl + l15*128 + (((4 + g) ^ swz) << 4));
    #pragma unroll
    for (int jd = 0; jd < 8; ++jd) {
      const bh8 vf0 = *(const bh8*)&Vs[cur][(jd*16 + l15)*64 + (((g    ) ^ swz) << 3)];
      const bh8 vf1 = *(const bh8*)&Vs[cur][(jd*16 + l15)*64 + (((4 + g) ^ swz) << 3)];
      acc[jd] = __builtin_amdgcn_mfma_f32_16x16x32_bf16(pa0, vf0, acc[jd], 0,0,0);
      acc[jd] = __builtin_amdgcn_mfma_f32_16x16x32_bf16(pa1, vf1, acc[jd], 0,0,0);
    }

    asm volatile("s_waitcnt vmcnt(0)" ::: "memory");
    __syncthreads();
  }
  #undef STAGE_KV

  // epilogue: complete the row sums (across the 4 lane-groups), redistribute
  // into acc row-space, normalize, store.
  lL += __shfl_xor(lL, 16, 64);
  lL += __shfl_xor(lL, 32, 64);
  float lar[4];
  #pragma unroll
  for (int r = 0; r < 4; ++r)
    lar[r] = __shfl(lL, (lane & 48) | (lr4 + r), 64);
  #pragma unroll
  for (int r = 0; r < 4; ++r) {
    const float inv = 1.f / lar[r];
    const int row = q0w + lr4 + r;
    bf16* orow = att + ((size_t)(b*T_ + row))*(NH_*HD_) + h*HD_;
    #pragma unroll
    for (int jd = 0; jd < 8; ++jd)
      orow[jd*16 + l15] = __float2bfloat16(acc[jd][r] * inv);
  }
}

extern "C" void kernel_launch(void* const* d_in, const int* in_sizes, int n_in,
                              void* d_out, int out_size, void* d_ws, size_t ws_size,
                              hipStream_t stream) {
  const float* x  = (const float*)d_in[0];
  const float* Wq = (const float*)d_in[1];
  const float* Wk = (const float*)d_in[2];
  const float* Wv = (const float*)d_in[3];
  const float* Wo = (const float*)d_in[4];
  const float* qw = (const float*)d_in[5];
  const float* kw = (const float*)d_in[6];
  float* out = (float*)d_out;

  char* ws = (char*)d_ws;
  bf16* xb   = (bf16*)(ws);                  // 16MB  (-> att later)
  bf16* Wqb  = (bf16*)(ws + (16u<<20));      // 8MB
  bf16* Wkb  = (bf16*)(ws + (24u<<20));      // 2MB
  bf16* Wvb  = (bf16*)(ws + (26u<<20));      // 2MB
  bf16* Wob  = (bf16*)(ws + (28u<<20));      // 8MB
  bf16* kbuf = (bf16*)(ws + (36u<<20));      // 4MB
  bf16* vraw = (bf16*)(ws + (40u<<20));      // 4MB
  bf16* Vt   = (bf16*)(ws + (44u<<20));      // 4MB
  bf16* att  = xb;
  bf16* qbuf = (bf16*)d_out;                 // Q scratch in d_out

  cvt32to16<<<dim3(2048), 256, 0, stream>>>(x,  xb,  M_*H_);
  cvt32to16<<<dim3(1024), 256, 0, stream>>>(Wq, Wqb, NH_*HD_*H_);
  cvt32to16<<<dim3(256),  256, 0, stream>>>(Wk, Wkb, NKV_*HD_*H_);
  cvt32to16<<<dim3(256),  256, 0, stream>>>(Wv, Wvb, NKV_*HD_*H_);
  cvt32to16<<<dim3(1024), 256, 0, stream>>>(Wo, Wob, H_*NH_*HD_);

  // fused QKV: N = 2048(Q) + 512(K) + 512(V) = 3072 -> 16m x 12n = 192 blocks
  gemm256<bf16><<<dim3(192), 512, 0, stream>>>(xb, Wqb, Wkb, Wvb,
                                               qbuf, kbuf, vraw,
                                               2048, 12, 8, 10, 2048);
  postproc<<<dim3(M_), 256, 0, stream>>>(qbuf, kbuf, qw, kw);
  vtrans<<<dim3(T_/64, (NKV_*HD_)/64, B_), 256, 0, stream>>>(vraw, Vt);
  attn<<<dim3(512), 512, 0, stream>>>(qbuf, kbuf, Vt, att);
  // O-proj: 16m x 8n = 128 blocks, fp32 out
  gemm256<float><<<dim3(128), 512, 0, stream>>>(att, Wob, Wob, Wob,
                                                out, out, out,
                                                2048, 8, 99, 99, 2048);
}

// Round 16
// 218.734 us; speedup vs baseline: 1.1741x; 1.1244x over previous
//
#include <hip/hip_runtime.h>
#include <hip/hip_bf16.h>
#include <stdint.h>

#define B_   2
#define T_   2048
#define H_   2048
#define NH_  16
#define NKV_ 4
#define HD_  128
#define M_   (B_*T_)
#define SCALE_  0.08838834764831845f
#define SCALE2_ (0.08838834764831845f * 1.4426950408889634f)   // scale * log2(e)

typedef __hip_bfloat16 bf16;
typedef __attribute__((ext_vector_type(8))) short bh8;
typedef __attribute__((ext_vector_type(4))) float f32x4;
typedef __attribute__((ext_vector_type(4))) unsigned short us4;

__device__ __forceinline__ void gload16(const bf16* g, bf16* l) {
  __builtin_amdgcn_global_load_lds(
      (const __attribute__((address_space(1))) void*)g,
      (__attribute__((address_space(3))) void*)l, 16, 0, 0);
}

__device__ __forceinline__ void cstore(bf16* p, float v)  { *p = __float2bfloat16(v); }
__device__ __forceinline__ void cstore(float* p, float v) { *p = v; }

__device__ __forceinline__ void cvt8(const float* src, bf16* dst, int i) {
  const float4 a = *(const float4*)(src + i);
  const float4 b = *(const float4*)(src + i + 4);
  bf16 o[8];
  o[0]=__float2bfloat16(a.x); o[1]=__float2bfloat16(a.y);
  o[2]=__float2bfloat16(a.z); o[3]=__float2bfloat16(a.w);
  o[4]=__float2bfloat16(b.x); o[5]=__float2bfloat16(b.y);
  o[6]=__float2bfloat16(b.z); o[7]=__float2bfloat16(b.w);
  *(bh8*)(dst + i) = *(const bh8*)o;
}

// fp32 -> bf16 elementwise (n multiple of 8)
__global__ __launch_bounds__(256) void cvt32to16(const float* __restrict__ src,
                                                 bf16* __restrict__ dst, int n)
{
  const int stride = gridDim.x * 256 * 8;
  for (int i = (blockIdx.x * 256 + threadIdx.x) * 8; i < n; i += stride)
    cvt8(src, dst, i);
}

// all 4 weight converts in one launch: blocks [0,512) Wq, [512,1024) Wo,
// [1024,1152) Wk, [1152,1280) Wv
__global__ __launch_bounds__(256) void cvtw(
    const float* __restrict__ q, bf16* __restrict__ qo,
    const float* __restrict__ o, bf16* __restrict__ oo,
    const float* __restrict__ k, bf16* __restrict__ ko,
    const float* __restrict__ v, bf16* __restrict__ vo)
{
  const int b = blockIdx.x;
  const float* src; bf16* dst; int n, b0, gb;
  if (b < 512)       { src=q; dst=qo; n=NH_*HD_*H_;  b0=b;      gb=512; }
  else if (b < 1024) { src=o; dst=oo; n=H_*NH_*HD_;  b0=b-512;  gb=512; }
  else if (b < 1152) { src=k; dst=ko; n=NKV_*HD_*H_; b0=b-1024; gb=128; }
  else               { src=v; dst=vo; n=NKV_*HD_*H_; b0=b-1152; gb=128; }
  const int stride = gb * 256 * 8;
  for (int i = (b0*256 + threadIdx.x)*8; i < n; i += stride)
    cvt8(src, dst, i);
}

// ---------------------------------------------------------------------------
// 256x256 8-phase GEMM (unchanged): serves fused QKV via N-split decode.
// ---------------------------------------------------------------------------
template<typename OutT>
__global__ __launch_bounds__(512, 2) void gemm256(
    const bf16* __restrict__ A,
    const bf16* __restrict__ W0, const bf16* __restrict__ W1, const bf16* __restrict__ W2,
    OutT* __restrict__ C0, OutT* __restrict__ C1, OutT* __restrict__ C2,
    int K, int nbN, int t1, int t2, int N0)
{
  const int bid = blockIdx.x;
  const int mb = bid / nbN, nb = bid % nbN;
  const int m0 = mb * 256;
  const int n0g = nb * 256;
  const bf16* W; OutT* C; int Nloc, nc0;
  if (nb < t1)      { W = W0 + (size_t)n0g*K;            C = C0; Nloc = N0;  nc0 = n0g; }
  else if (nb < t2) { W = W1 + (size_t)(n0g - t1*256)*K; C = C1; Nloc = 512; nc0 = n0g - t1*256; }
  else              { W = W2 + (size_t)(n0g - t2*256)*K; C = C2; Nloc = 512; nc0 = n0g - t2*256; }
  const bf16* Ag = A + (size_t)m0 * K;

  const int tid = threadIdx.x, lane = tid & 63, w = tid >> 6;
  const int wm = w >> 2, wn = w & 3;
  const int l15 = lane & 15, g = lane >> 4;
  const int swz = l15 & 7;

  __shared__ bf16 LA[2][256*64];
  __shared__ bf16 LB[2][256*64];

  f32x4 acc[8][4] = {};
  bh8 bfr[4][2];

  const int ktmask = (K >> 6) - 1;
  const int niter  = K >> 7;

  #define STG(DST, SRC, KT, HALF)                                                   \
    { _Pragma("unroll")                                                             \
      for (int i_ = 0; i_ < 2; ++i_) {                                              \
        const int o_ = i_*512 + tid; const int r_ = o_ >> 3; const int sl_ = o_ & 7;\
        gload16((SRC) + (size_t)((HALF)*128 + r_)*K + (KT)*64 + ((sl_ ^ (r_ & 7)) << 3), \
                (DST) + (HALF)*8192 + o_*8);                                        \
      } }

  STG(LA[0], Ag, 0, 0); STG(LA[0], Ag, 0, 1);
  STG(LB[0], W,  0, 0); STG(LB[0], W,  0, 1);
  STG(LB[1], W,  1, 0); STG(LB[1], W,  1, 1);
  asm volatile("s_waitcnt vmcnt(4)" ::: "memory");
  __builtin_amdgcn_s_barrier();

  #define PHASE(MI0, RBUF, DOB, SDST, SSRC, SKT, SHALF, CHK)                        \
    {                                                                               \
      if (DOB) {                                                                    \
        _Pragma("unroll") for (int nj=0;nj<4;++nj)                                  \
        _Pragma("unroll") for (int ks=0;ks<2;++ks)                                  \
          bfr[nj][ks] = *(const bh8*)&LB[RBUF][(wn*64+nj*16+l15)*64 + (((ks*4+g)^swz)<<3)]; \
      }                                                                             \
      bh8 af_[2][2];                                                                \
      _Pragma("unroll") for (int mi=0;mi<2;++mi)                                    \
      _Pragma("unroll") for (int ks=0;ks<2;++ks)                                    \
        af_[mi][ks] = *(const bh8*)&LA[RBUF][(wm*128+((MI0)+mi)*16+l15)*64 + (((ks*4+g)^swz)<<3)]; \
      STG(SDST, SSRC, SKT, SHALF);                                                  \
      __builtin_amdgcn_s_barrier();                                                 \
      asm volatile("s_waitcnt lgkmcnt(0)" ::: "memory");                            \
      __builtin_amdgcn_sched_barrier(0);                                            \
      __builtin_amdgcn_s_setprio(1);                                                \
      _Pragma("unroll") for (int mi=0;mi<2;++mi)                                    \
      _Pragma("unroll") for (int nj=0;nj<4;++nj) {                                  \
        acc[(MI0)+mi][nj] = __builtin_amdgcn_mfma_f32_16x16x32_bf16(af_[mi][0], bfr[nj][0], acc[(MI0)+mi][nj],0,0,0); \
        acc[(MI0)+mi][nj] = __builtin_amdgcn_mfma_f32_16x16x32_bf16(af_[mi][1], bfr[nj][1], acc[(MI0)+mi][nj],0,0,0); \
      }                                                                             \
      __builtin_amdgcn_s_setprio(0);                                                \
      if (CHK) { asm volatile("s_waitcnt vmcnt(4)" ::: "memory"); }                 \
      __builtin_amdgcn_s_barrier();                                                 \
    }

  for (int j = 0; j < niter; ++j) {
    const int kta = 2*j + 1;
    const int ktb = (2*j + 2) & ktmask;
    const int ktc = (2*j + 3) & ktmask;
    PHASE(0, 0, true , LA[1], Ag, kta, 0, false)
    PHASE(2, 0, false, LA[1], Ag, kta, 1, false)
    PHASE(4, 0, false, LB[0], W,  ktb, 0, false)
    PHASE(6, 0, false, LB[0], W,  ktb, 1, true )
    PHASE(0, 1, true , LA[0], Ag, ktb, 0, false)
    PHASE(2, 1, false, LA[0], Ag, ktb, 1, false)
    PHASE(4, 1, false, LB[1], W,  ktc, 0, false)
    PHASE(6, 1, false, LB[1], W,  ktc, 1, true )
  }
  #undef PHASE
  #undef STG

  #pragma unroll
  for (int mi = 0; mi < 8; ++mi)
    #pragma unroll
    for (int r = 0; r < 4; ++r) {
      const int row = m0 + wm*128 + mi*16 + (lane>>4)*4 + r;
      #pragma unroll
      for (int nj = 0; nj < 4; ++nj) {
        const int col = nc0 + wn*64 + nj*16 + l15;
        cstore(&C[(size_t)row*Nloc + col], acc[mi][nj][r]);
      }
    }
}

// ---------------------------------------------------------------------------
// 256x128 8-phase GEMM: same schedule with B = one stage slot per K-tile.
// Phases 4 & 8 stage nothing and carry vmcnt(2) (queue never drains to 0).
// 256 blocks for O-proj (N=2048) -> exactly 1 block/CU.
// ---------------------------------------------------------------------------
template<typename OutT>
__global__ __launch_bounds__(512, 2) void gemm_n128(
    const bf16* __restrict__ A, const bf16* __restrict__ Wm, OutT* __restrict__ C,
    int K, int nbN, int N)
{
  const int bid = blockIdx.x;
  const int m0 = (bid / nbN) * 256;
  const int n0 = (bid % nbN) * 128;
  const bf16* W  = Wm + (size_t)n0 * K;
  const bf16* Ag = A  + (size_t)m0 * K;

  const int tid = threadIdx.x, lane = tid & 63, w = tid >> 6;
  const int wm = w >> 2, wn = w & 3;
  const int l15 = lane & 15, g = lane >> 4;
  const int swz = l15 & 7;

  __shared__ bf16 LA[2][256*64];   // 2 x 32 KiB
  __shared__ bf16 LB[2][128*64];   // 2 x 16 KiB (total 96 KiB)

  f32x4 acc[8][2] = {};
  bh8 bfr[2][2];

  const int ktmask = (K >> 6) - 1;
  const int niter  = K >> 7;

  #define STG2(DST, SRC, KT, HALF)                                                  \
    { _Pragma("unroll")                                                             \
      for (int i_ = 0; i_ < 2; ++i_) {                                              \
        const int o_ = i_*512 + tid; const int r_ = o_ >> 3; const int sl_ = o_ & 7;\
        gload16((SRC) + (size_t)((HALF)*128 + r_)*K + (KT)*64 + ((sl_ ^ (r_ & 7)) << 3), \
                (DST) + (HALF)*8192 + o_*8);                                        \
      } }

  // prologue: LA0<-A kt0 (4), LB0<-B kt0 (2), LB1<-B kt1 (2); need LA0+LB0
  STG2(LA[0], Ag, 0, 0); STG2(LA[0], Ag, 0, 1);
  STG2(LB[0], W,  0, 0);
  STG2(LB[1], W,  1, 0);
  asm volatile("s_waitcnt vmcnt(2)" ::: "memory");
  __builtin_amdgcn_s_barrier();

  #define PH2_CORE(MI0, RBUF)                                                       \
      bh8 af_[2][2];                                                                \
      _Pragma("unroll") for (int mi=0;mi<2;++mi)                                    \
      _Pragma("unroll") for (int ks=0;ks<2;++ks)                                    \
        af_[mi][ks] = *(const bh8*)&LA[RBUF][(wm*128+((MI0)+mi)*16+l15)*64 + (((ks*4+g)^swz)<<3)];

  #define PH2_TAIL(MI0, RBUF, CHK)                                                  \
      __builtin_amdgcn_s_barrier();                                                 \
      asm volatile("s_waitcnt lgkmcnt(0)" ::: "memory");                            \
      __builtin_amdgcn_sched_barrier(0);                                            \
      __builtin_amdgcn_s_setprio(1);                                                \
      _Pragma("unroll") for (int mi=0;mi<2;++mi)                                    \
      _Pragma("unroll") for (int nj=0;nj<2;++nj) {                                  \
        acc[(MI0)+mi][nj] = __builtin_amdgcn_mfma_f32_16x16x32_bf16(af_[mi][0], bfr[nj][0], acc[(MI0)+mi][nj],0,0,0); \
        acc[(MI0)+mi][nj] = __builtin_amdgcn_mfma_f32_16x16x32_bf16(af_[mi][1], bfr[nj][1], acc[(MI0)+mi][nj],0,0,0); \
      }                                                                             \
      __builtin_amdgcn_s_setprio(0);                                                \
      if (CHK) { asm volatile("s_waitcnt vmcnt(2)" ::: "memory"); }                 \
      __builtin_amdgcn_s_barrier();

  #define PHASE2S(MI0, RBUF, DOB, SDST, SSRC, SKT, SHALF)                           \
    {                                                                               \
      if (DOB) {                                                                    \
        _Pragma("unroll") for (int nj=0;nj<2;++nj)                                  \
        _Pragma("unroll") for (int ks=0;ks<2;++ks)                                  \
          bfr[nj][ks] = *(const bh8*)&LB[RBUF][(wn*32+nj*16+l15)*64 + (((ks*4+g)^swz)<<3)]; \
      }                                                                             \
      PH2_CORE(MI0, RBUF)                                                           \
      STG2(SDST, SSRC, SKT, SHALF);                                                 \
      PH2_TAIL(MI0, RBUF, false)                                                    \
    }

  #define PHASE2N(MI0, RBUF)                                                        \
    {                                                                               \
      PH2_CORE(MI0, RBUF)                                                           \
      PH2_TAIL(MI0, RBUF, true)                                                     \
    }

  for (int j = 0; j < niter; ++j) {
    const int kta = 2*j + 1;
    const int ktb = (2*j + 2) & ktmask;
    const int ktc = (2*j + 3) & ktmask;
    PHASE2S(0, 0, true , LA[1], Ag, kta, 0)
    PHASE2S(2, 0, false, LA[1], Ag, kta, 1)
    PHASE2S(4, 0, false, LB[0], W,  ktb, 0)
    PHASE2N(6, 0)
    PHASE2S(0, 1, true , LA[0], Ag, ktb, 0)
    PHASE2S(2, 1, false, LA[0], Ag, ktb, 1)
    PHASE2S(4, 1, false, LB[1], W,  ktc, 0)
    PHASE2N(6, 1)
  }
  #undef PHASE2S
  #undef PHASE2N
  #undef PH2_CORE
  #undef PH2_TAIL
  #undef STG2

  #pragma unroll
  for (int mi = 0; mi < 8; ++mi)
    #pragma unroll
    for (int r = 0; r < 4; ++r) {
      const int row = m0 + wm*128 + mi*16 + (lane>>4)*4 + r;
      #pragma unroll
      for (int nj = 0; nj < 2; ++nj) {
        const int col = n0 + wn*32 + nj*16 + l15;
        cstore(&C[(size_t)row*N + col], acc[mi][nj][r]);
      }
    }
}

// Per (b,t): RMSNorm(HD) + RoPE IN PLACE. Lane l owns d=l and d=l+64.
// Q additionally pre-multiplied by SCALE2_ (attn softmax uses raw exp2).
__global__ __launch_bounds__(256) void postproc(
    bf16* __restrict__ q, bf16* __restrict__ k,
    const float* __restrict__ qw, const float* __restrict__ kw)
{
  const int blk  = blockIdx.x;
  const int t    = blk & (T_-1);
  const int lane = threadIdx.x & 63;
  const int w    = threadIdx.x >> 6;

  const float inv = expf(-(float)lane * (9.210340371976184f / 64.f));
  const float ang = (float)t * inv;
  const float cw = cosf(ang), sw = sinf(ang);

  #pragma unroll
  for (int hi = 0; hi < 4; ++hi) {
    const int h = w + hi*4;
    bf16* row = q + (size_t)blk*(NH_*HD_) + h*HD_;
    float x1 = __bfloat162float(row[lane]);
    float x2 = __bfloat162float(row[lane+64]);
    float ss = x1*x1 + x2*x2;
    #pragma unroll
    for (int m = 1; m < 64; m <<= 1) ss += __shfl_xor(ss, m, 64);
    const float rs = rsqrtf(ss*(1.f/128.f) + 1e-6f);
    const float n1 = x1*rs*(1.f + qw[lane]), n2 = x2*rs*(1.f + qw[lane+64]);
    row[lane]    = __float2bfloat16((n1*cw - n2*sw) * SCALE2_);
    row[lane+64] = __float2bfloat16((n2*cw + n1*sw) * SCALE2_);
  }
  {
    bf16* row = k + (size_t)blk*(NKV_*HD_) + w*HD_;
    float x1 = __bfloat162float(row[lane]);
    float x2 = __bfloat162float(row[lane+64]);
    float ss = x1*x1 + x2*x2;
    #pragma unroll
    for (int m = 1; m < 64; m <<= 1) ss += __shfl_xor(ss, m, 64);
    const float rs = rsqrtf(ss*(1.f/128.f) + 1e-6f);
    const float n1 = x1*rs*(1.f + kw[lane]), n2 = x2*rs*(1.f + kw[lane+64]);
    row[lane]    = __float2bfloat16(n1*cw - n2*sw);
    row[lane+64] = __float2bfloat16(n2*cw + n1*sw);
  }
}

// v_raw [b*T+t][kvh*128+d]  ->  Vt [b][kvh][d][T]
__global__ __launch_bounds__(256) void vtrans(const bf16* __restrict__ vraw,
                                              bf16* __restrict__ Vt)
{
  __shared__ bf16 tile[64][65];
  const int t0 = blockIdx.x * 64;
  const int c0 = blockIdx.y * 64;
  const int b  = blockIdx.z;
  const int tx = threadIdx.x & 63;
  const int ty = threadIdx.x >> 6;
  const bf16* src = vraw + (size_t)b * T_ * (NKV_*HD_);
  bf16* dst       = Vt   + (size_t)b * (NKV_*HD_) * T_;
  #pragma unroll
  for (int i = 0; i < 16; ++i) {
    const int r = i*4 + ty;
    tile[r][tx] = src[(size_t)(t0 + r)*(NKV_*HD_) + c0 + tx];
  }
  __syncthreads();
  #pragma unroll
  for (int i = 0; i < 16; ++i) {
    const int r = i*4 + ty;
    dst[(size_t)(c0 + r)*T_ + t0 + tx] = tile[tx][r];
  }
}

// Flash attention v9 (unchanged from round 15): fixed-shift softmax,
// GQA-shared double-buffered K/V, prefetch-before-compute, 80 KiB LDS.
__global__ __launch_bounds__(512, 4) void attn(
    const bf16* __restrict__ Q, const bf16* __restrict__ Kb,
    const bf16* __restrict__ Vt, bf16* __restrict__ att)
{
  const int id  = blockIdx.x;
  const int s   = 63 - (id >> 3);
  const int kvh = (id >> 1) & 3;
  const int b   = id & 1;
  const int tid = threadIdx.x, lane = tid & 63, w = tid >> 6;
  const int h   = kvh*4 + (w & 3);
  const int l15 = lane & 15;
  const int g   = lane >> 4;
  const int lr4 = g * 4;
  const int swz = l15 & 7;

  const int q0w = s*32 + (w >> 2)*16;
  const int nt  = (s >> 1) + 1;

  __shared__ bf16 Ks[2][64*128];
  __shared__ bf16 Vs[2][128*64];
  __shared__ bf16 Plds[8][16*64];

  const bf16* Kglob = Kb + (size_t)b*T_*(NKV_*HD_) + kvh*HD_;
  const bf16* Vglob = Vt + (size_t)(b*NKV_ + kvh)*HD_*T_;

  bh8 aQ[4];
  #pragma unroll
  for (int kk = 0; kk < 4; ++kk)
    aQ[kk] = *(const bh8*)&Q[(size_t)(b*T_ + q0w + l15)*(NH_*HD_) + h*HD_ + kk*32 + g*8];

  f32x4 acc[8] = {};
  float lL = 0.f;

  #define STAGE_KV(buf, kv0s)                                                   \
    {                                                                           \
      _Pragma("unroll")                                                         \
      for (int i = 0; i < 2; ++i) {                                             \
        const int o = i*512 + tid;                                              \
        const int r = o >> 4, sl = o & 15;                                      \
        gload16(Kglob + (size_t)((kv0s) + r)*(NKV_*HD_) + ((sl ^ (r & 7)) << 3),\
                &Ks[buf][o*8]);                                                 \
      }                                                                         \
      _Pragma("unroll")                                                         \
      for (int i = 0; i < 2; ++i) {                                             \
        const int o = i*512 + tid;                                              \
        const int d = o >> 3, sl = o & 7;                                       \
        gload16(Vglob + (size_t)d*T_ + (kv0s) + ((sl ^ (d & 7)) << 3),          \
                &Vs[buf][o*8]);                                                 \
      }                                                                         \
    }

  STAGE_KV(0, 0);
  asm volatile("s_waitcnt vmcnt(0)" ::: "memory");
  __syncthreads();

  for (int j = 0; j < nt; ++j) {
    const int cur = j & 1;
    const int kv0 = j*64;

    if (j + 1 < nt) STAGE_KV(cur ^ 1, kv0 + 64);

    f32x4 S[4] = {};
    #pragma unroll
    for (int jb = 0; jb < 4; ++jb)
      #pragma unroll
      for (int kk = 0; kk < 4; ++kk) {
        const bh8 kf = *(const bh8*)&Ks[cur][(jb*16 + l15)*128 + (((kk*4 + g) ^ swz) << 3)];
        S[jb] = __builtin_amdgcn_mfma_f32_16x16x32_bf16(kf, aQ[kk], S[jb], 0,0,0);
      }

    const bool diag = (j == nt - 1);
    float sv[16];
    float sum = 0.f;
    #pragma unroll
    for (int jb = 0; jb < 4; ++jb)
      #pragma unroll
      for (int r = 0; r < 4; ++r) {
        float sc = S[jb][r];
        if (diag && (kv0 + jb*16 + lr4 + r) > (q0w + l15)) sc = -1e30f;
        const float p = exp2f(sc);
        sv[jb*4 + r] = p;
        sum += p;
      }
    lL += sum;

    bf16* pl = Plds[w];
    #pragma unroll
    for (int jb = 0; jb < 4; ++jb) {
      bf16 pk[4];
      #pragma unroll
      for (int r = 0; r < 4; ++r) pk[r] = __float2bfloat16(sv[jb*4 + r]);
      *(us4*)((char*)pl + l15*128 + ((((jb<<1) | (g>>1)) ^ swz) << 4) + ((g&1) << 3))
          = *(const us4*)pk;
    }

    asm volatile("s_waitcnt lgkmcnt(0)" ::: "memory");
    __builtin_amdgcn_sched_barrier(0);

    const bh8 pa0 = *(const bh8*)((const char*)pl + l15*128 + (((g    ) ^ swz) << 4));
    const bh8 pa1 = *(const bh8*)((const char*)pl + l15*128 + (((4 + g) ^ swz) << 4));
    #pragma unroll
    for (int jd = 0; jd < 8; ++jd) {
      const bh8 vf0 = *(const bh8*)&Vs[cur][(jd*16 + l15)*64 + (((g    ) ^ swz) << 3)];
      const bh8 vf1 = *(const bh8*)&Vs[cur][(jd*16 + l15)*64 + (((4 + g) ^ swz) << 3)];
      acc[jd] = __builtin_amdgcn_mfma_f32_16x16x32_bf16(pa0, vf0, acc[jd], 0,0,0);
      acc[jd] = __builtin_amdgcn_mfma_f32_16x16x32_bf16(pa1, vf1, acc[jd], 0,0,0);
    }

    asm volatile("s_waitcnt vmcnt(0)" ::: "memory");
    __syncthreads();
  }
  #undef STAGE_KV

  lL += __shfl_xor(lL, 16, 64);
  lL += __shfl_xor(lL, 32, 64);
  float lar[4];
  #pragma unroll
  for (int r = 0; r < 4; ++r)
    lar[r] = __shfl(lL, (lane & 48) | (lr4 + r), 64);
  #pragma unroll
  for (int r = 0; r < 4; ++r) {
    const float inv = 1.f / lar[r];
    const int row = q0w + lr4 + r;
    bf16* orow = att + ((size_t)(b*T_ + row))*(NH_*HD_) + h*HD_;
    #pragma unroll
    for (int jd = 0; jd < 8; ++jd)
      orow[jd*16 + l15] = __float2bfloat16(acc[jd][r] * inv);
  }
}

extern "C" void kernel_launch(void* const* d_in, const int* in_sizes, int n_in,
                              void* d_out, int out_size, void* d_ws, size_t ws_size,
                              hipStream_t stream) {
  const float* x  = (const float*)d_in[0];
  const float* Wq = (const float*)d_in[1];
  const float* Wk = (const float*)d_in[2];
  const float* Wv = (const float*)d_in[3];
  const float* Wo = (const float*)d_in[4];
  const float* qw = (const float*)d_in[5];
  const float* kw = (const float*)d_in[6];
  float* out = (float*)d_out;

  char* ws = (char*)d_ws;
  bf16* xb   = (bf16*)(ws);                  // 16MB  (-> att later)
  bf16* Wqb  = (bf16*)(ws + (16u<<20));      // 8MB
  bf16* Wkb  = (bf16*)(ws + (24u<<20));      // 2MB
  bf16* Wvb  = (bf16*)(ws + (26u<<20));      // 2MB
  bf16* Wob  = (bf16*)(ws + (28u<<20));      // 8MB
  bf16* kbuf = (bf16*)(ws + (36u<<20));      // 4MB
  bf16* vraw = (bf16*)(ws + (40u<<20));      // 4MB
  bf16* Vt   = (bf16*)(ws + (44u<<20));      // 4MB
  bf16* att  = xb;
  bf16* qbuf = (bf16*)d_out;                 // Q scratch in d_out

  cvt32to16<<<dim3(2048), 256, 0, stream>>>(x, xb, M_*H_);
  cvtw<<<dim3(1280), 256, 0, stream>>>(Wq, Wqb, Wo, Wob, Wk, Wkb, Wv, Wvb);

  // fused QKV: N = 2048(Q) + 512(K) + 512(V) = 3072 -> 16m x 12n = 192 blocks
  gemm256<bf16><<<dim3(192), 512, 0, stream>>>(xb, Wqb, Wkb, Wvb,
                                               qbuf, kbuf, vraw,
                                               2048, 12, 8, 10, 2048);
  postproc<<<dim3(M_), 256, 0, stream>>>(qbuf, kbuf, qw, kw);
  vtrans<<<dim3(T_/64, (NKV_*HD_)/64, B_), 256, 0, stream>>>(vraw, Vt);
  attn<<<dim3(512), 512, 0, stream>>>(qbuf, kbuf, Vt, att);
  // O-proj: 256x128 tiles -> 16m x 16n = 256 blocks (1/CU), fp32 out
  gemm_n128<float><<<dim3(256), 512, 0, stream>>>(att, Wob, out, 2048, 16, 2048);
}

// Round 17
// 214.839 us; speedup vs baseline: 1.1954x; 1.0181x over previous
//
#include <hip/hip_runtime.h>
#include <hip/hip_bf16.h>
#include <stdint.h>

#define B_   2
#define T_   2048
#define H_   2048
#define NH_  16
#define NKV_ 4
#define HD_  128
#define M_   (B_*T_)
#define SCALE_  0.08838834764831845f
#define SCALE2_ (0.08838834764831845f * 1.4426950408889634f)   // scale * log2(e)

typedef __hip_bfloat16 bf16;
typedef __attribute__((ext_vector_type(8))) short bh8;
typedef __attribute__((ext_vector_type(4))) float f32x4;
typedef __attribute__((ext_vector_type(4))) unsigned short us4;

__device__ __forceinline__ void gload16(const bf16* g, bf16* l) {
  __builtin_amdgcn_global_load_lds(
      (const __attribute__((address_space(1))) void*)g,
      (__attribute__((address_space(3))) void*)l, 16, 0, 0);
}

__device__ __forceinline__ void cstore(bf16* p, float v)  { *p = __float2bfloat16(v); }
__device__ __forceinline__ void cstore(float* p, float v) { *p = v; }

__device__ __forceinline__ void cvt8(const float* src, bf16* dst, int i) {
  const float4 a = *(const float4*)(src + i);
  const float4 b = *(const float4*)(src + i + 4);
  bf16 o[8];
  o[0]=__float2bfloat16(a.x); o[1]=__float2bfloat16(a.y);
  o[2]=__float2bfloat16(a.z); o[3]=__float2bfloat16(a.w);
  o[4]=__float2bfloat16(b.x); o[5]=__float2bfloat16(b.y);
  o[6]=__float2bfloat16(b.z); o[7]=__float2bfloat16(b.w);
  *(bh8*)(dst + i) = *(const bh8*)o;
}

// fp32 -> bf16 elementwise (n multiple of 8)
__global__ __launch_bounds__(256) void cvt32to16(const float* __restrict__ src,
                                                 bf16* __restrict__ dst, int n)
{
  const int stride = gridDim.x * 256 * 8;
  for (int i = (blockIdx.x * 256 + threadIdx.x) * 8; i < n; i += stride)
    cvt8(src, dst, i);
}

// all 4 weight converts in one launch
__global__ __launch_bounds__(256) void cvtw(
    const float* __restrict__ q, bf16* __restrict__ qo,
    const float* __restrict__ o, bf16* __restrict__ oo,
    const float* __restrict__ k, bf16* __restrict__ ko,
    const float* __restrict__ v, bf16* __restrict__ vo)
{
  const int b = blockIdx.x;
  const float* src; bf16* dst; int n, b0, gb;
  if (b < 512)       { src=q; dst=qo; n=NH_*HD_*H_;  b0=b;      gb=512; }
  else if (b < 1024) { src=o; dst=oo; n=H_*NH_*HD_;  b0=b-512;  gb=512; }
  else if (b < 1152) { src=k; dst=ko; n=NKV_*HD_*H_; b0=b-1024; gb=128; }
  else               { src=v; dst=vo; n=NKV_*HD_*H_; b0=b-1152; gb=128; }
  const int stride = gb * 256 * 8;
  for (int i = (b0*256 + threadIdx.x)*8; i < n; i += stride)
    cvt8(src, dst, i);
}

// ---------------------------------------------------------------------------
// 256x256 8-phase GEMM with XCD-chunked block swizzle (grid must be mult of 8).
// ---------------------------------------------------------------------------
template<typename OutT>
__global__ __launch_bounds__(512, 2) void gemm256(
    const bf16* __restrict__ A,
    const bf16* __restrict__ W0, const bf16* __restrict__ W1, const bf16* __restrict__ W2,
    OutT* __restrict__ C0, OutT* __restrict__ C1, OutT* __restrict__ C2,
    int K, int nbN, int t1, int t2, int N0, int cpx)
{
  const int bid = (int)(blockIdx.x & 7) * cpx + (int)(blockIdx.x >> 3);  // T1 swizzle
  const int mb = bid / nbN, nb = bid % nbN;
  const int m0 = mb * 256;
  const int n0g = nb * 256;
  const bf16* W; OutT* C; int Nloc, nc0;
  if (nb < t1)      { W = W0 + (size_t)n0g*K;            C = C0; Nloc = N0;  nc0 = n0g; }
  else if (nb < t2) { W = W1 + (size_t)(n0g - t1*256)*K; C = C1; Nloc = 512; nc0 = n0g - t1*256; }
  else              { W = W2 + (size_t)(n0g - t2*256)*K; C = C2; Nloc = 512; nc0 = n0g - t2*256; }
  const bf16* Ag = A + (size_t)m0 * K;

  const int tid = threadIdx.x, lane = tid & 63, w = tid >> 6;
  const int wm = w >> 2, wn = w & 3;
  const int l15 = lane & 15, g = lane >> 4;
  const int swz = l15 & 7;

  __shared__ bf16 LA[2][256*64];
  __shared__ bf16 LB[2][256*64];

  f32x4 acc[8][4] = {};
  bh8 bfr[4][2];

  const int ktmask = (K >> 6) - 1;
  const int niter  = K >> 7;

  #define STG(DST, SRC, KT, HALF)                                                   \
    { _Pragma("unroll")                                                             \
      for (int i_ = 0; i_ < 2; ++i_) {                                              \
        const int o_ = i_*512 + tid; const int r_ = o_ >> 3; const int sl_ = o_ & 7;\
        gload16((SRC) + (size_t)((HALF)*128 + r_)*K + (KT)*64 + ((sl_ ^ (r_ & 7)) << 3), \
                (DST) + (HALF)*8192 + o_*8);                                        \
      } }

  STG(LA[0], Ag, 0, 0); STG(LA[0], Ag, 0, 1);
  STG(LB[0], W,  0, 0); STG(LB[0], W,  0, 1);
  STG(LB[1], W,  1, 0); STG(LB[1], W,  1, 1);
  asm volatile("s_waitcnt vmcnt(4)" ::: "memory");
  __builtin_amdgcn_s_barrier();

  #define PHASE(MI0, RBUF, DOB, SDST, SSRC, SKT, SHALF, CHK)                        \
    {                                                                               \
      if (DOB) {                                                                    \
        _Pragma("unroll") for (int nj=0;nj<4;++nj)                                  \
        _Pragma("unroll") for (int ks=0;ks<2;++ks)                                  \
          bfr[nj][ks] = *(const bh8*)&LB[RBUF][(wn*64+nj*16+l15)*64 + (((ks*4+g)^swz)<<3)]; \
      }                                                                             \
      bh8 af_[2][2];                                                                \
      _Pragma("unroll") for (int mi=0;mi<2;++mi)                                    \
      _Pragma("unroll") for (int ks=0;ks<2;++ks)                                    \
        af_[mi][ks] = *(const bh8*)&LA[RBUF][(wm*128+((MI0)+mi)*16+l15)*64 + (((ks*4+g)^swz)<<3)]; \
      STG(SDST, SSRC, SKT, SHALF);                                                  \
      __builtin_amdgcn_s_barrier();                                                 \
      asm volatile("s_waitcnt lgkmcnt(0)" ::: "memory");                            \
      __builtin_amdgcn_sched_barrier(0);                                            \
      __builtin_amdgcn_s_setprio(1);                                                \
      _Pragma("unroll") for (int mi=0;mi<2;++mi)                                    \
      _Pragma("unroll") for (int nj=0;nj<4;++nj) {                                  \
        acc[(MI0)+mi][nj] = __builtin_amdgcn_mfma_f32_16x16x32_bf16(af_[mi][0], bfr[nj][0], acc[(MI0)+mi][nj],0,0,0); \
        acc[(MI0)+mi][nj] = __builtin_amdgcn_mfma_f32_16x16x32_bf16(af_[mi][1], bfr[nj][1], acc[(MI0)+mi][nj],0,0,0); \
      }                                                                             \
      __builtin_amdgcn_s_setprio(0);                                                \
      if (CHK) { asm volatile("s_waitcnt vmcnt(4)" ::: "memory"); }                 \
      __builtin_amdgcn_s_barrier();                                                 \
    }

  for (int j = 0; j < niter; ++j) {
    const int kta = 2*j + 1;
    const int ktb = (2*j + 2) & ktmask;
    const int ktc = (2*j + 3) & ktmask;
    PHASE(0, 0, true , LA[1], Ag, kta, 0, false)
    PHASE(2, 0, false, LA[1], Ag, kta, 1, false)
    PHASE(4, 0, false, LB[0], W,  ktb, 0, false)
    PHASE(6, 0, false, LB[0], W,  ktb, 1, true )
    PHASE(0, 1, true , LA[0], Ag, ktb, 0, false)
    PHASE(2, 1, false, LA[0], Ag, ktb, 1, false)
    PHASE(4, 1, false, LB[1], W,  ktc, 0, false)
    PHASE(6, 1, false, LB[1], W,  ktc, 1, true )
  }
  #undef PHASE
  #undef STG

  #pragma unroll
  for (int mi = 0; mi < 8; ++mi)
    #pragma unroll
    for (int r = 0; r < 4; ++r) {
      const int row = m0 + wm*128 + mi*16 + (lane>>4)*4 + r;
      #pragma unroll
      for (int nj = 0; nj < 4; ++nj) {
        const int col = nc0 + wn*64 + nj*16 + l15;
        cstore(&C[(size_t)row*Nloc + col], acc[mi][nj][r]);
      }
    }
}

// ---------------------------------------------------------------------------
// 256x128 8-phase GEMM (O-proj), with XCD swizzle. Phases 4/8 stage nothing,
// vmcnt(2).
// ---------------------------------------------------------------------------
template<typename OutT>
__global__ __launch_bounds__(512, 2) void gemm_n128(
    const bf16* __restrict__ A, const bf16* __restrict__ Wm, OutT* __restrict__ C,
    int K, int nbN, int N, int cpx)
{
  const int bid = (int)(blockIdx.x & 7) * cpx + (int)(blockIdx.x >> 3);  // T1 swizzle
  const int m0 = (bid / nbN) * 256;
  const int n0 = (bid % nbN) * 128;
  const bf16* W  = Wm + (size_t)n0 * K;
  const bf16* Ag = A  + (size_t)m0 * K;

  const int tid = threadIdx.x, lane = tid & 63, w = tid >> 6;
  const int wm = w >> 2, wn = w & 3;
  const int l15 = lane & 15, g = lane >> 4;
  const int swz = l15 & 7;

  __shared__ bf16 LA[2][256*64];
  __shared__ bf16 LB[2][128*64];

  f32x4 acc[8][2] = {};
  bh8 bfr[2][2];

  const int ktmask = (K >> 6) - 1;
  const int niter  = K >> 7;

  #define STG2(DST, SRC, KT, HALF)                                                  \
    { _Pragma("unroll")                                                             \
      for (int i_ = 0; i_ < 2; ++i_) {                                              \
        const int o_ = i_*512 + tid; const int r_ = o_ >> 3; const int sl_ = o_ & 7;\
        gload16((SRC) + (size_t)((HALF)*128 + r_)*K + (KT)*64 + ((sl_ ^ (r_ & 7)) << 3), \
                (DST) + (HALF)*8192 + o_*8);                                        \
      } }

  STG2(LA[0], Ag, 0, 0); STG2(LA[0], Ag, 0, 1);
  STG2(LB[0], W,  0, 0);
  STG2(LB[1], W,  1, 0);
  asm volatile("s_waitcnt vmcnt(2)" ::: "memory");
  __builtin_amdgcn_s_barrier();

  #define PH2_CORE(MI0, RBUF)                                                       \
      bh8 af_[2][2];                                                                \
      _Pragma("unroll") for (int mi=0;mi<2;++mi)                                    \
      _Pragma("unroll") for (int ks=0;ks<2;++ks)                                    \
        af_[mi][ks] = *(const bh8*)&LA[RBUF][(wm*128+((MI0)+mi)*16+l15)*64 + (((ks*4+g)^swz)<<3)];

  #define PH2_TAIL(MI0, RBUF, CHK)                                                  \
      __builtin_amdgcn_s_barrier();                                                 \
      asm volatile("s_waitcnt lgkmcnt(0)" ::: "memory");                            \
      __builtin_amdgcn_sched_barrier(0);                                            \
      __builtin_amdgcn_s_setprio(1);                                                \
      _Pragma("unroll") for (int mi=0;mi<2;++mi)                                    \
      _Pragma("unroll") for (int nj=0;nj<2;++nj) {                                  \
        acc[(MI0)+mi][nj] = __builtin_amdgcn_mfma_f32_16x16x32_bf16(af_[mi][0], bfr[nj][0], acc[(MI0)+mi][nj],0,0,0); \
        acc[(MI0)+mi][nj] = __builtin_amdgcn_mfma_f32_16x16x32_bf16(af_[mi][1], bfr[nj][1], acc[(MI0)+mi][nj],0,0,0); \
      }                                                                             \
      __builtin_amdgcn_s_setprio(0);                                                \
      if (CHK) { asm volatile("s_waitcnt vmcnt(2)" ::: "memory"); }                 \
      __builtin_amdgcn_s_barrier();

  #define PHASE2S(MI0, RBUF, DOB, SDST, SSRC, SKT, SHALF)                           \
    {                                                                               \
      if (DOB) {                                                                    \
        _Pragma("unroll") for (int nj=0;nj<2;++nj)                                  \
        _Pragma("unroll") for (int ks=0;ks<2;++ks)                                  \
          bfr[nj][ks] = *(const bh8*)&LB[RBUF][(wn*32+nj*16+l15)*64 + (((ks*4+g)^swz)<<3)]; \
      }                                                                             \
      PH2_CORE(MI0, RBUF)                                                           \
      STG2(SDST, SSRC, SKT, SHALF);                                                 \
      PH2_TAIL(MI0, RBUF, false)                                                    \
    }

  #define PHASE2N(MI0, RBUF)                                                        \
    {                                                                               \
      PH2_CORE(MI0, RBUF)                                                           \
      PH2_TAIL(MI0, RBUF, true)                                                     \
    }

  for (int j = 0; j < niter; ++j) {
    const int kta = 2*j + 1;
    const int ktb = (2*j + 2) & ktmask;
    const int ktc = (2*j + 3) & ktmask;
    PHASE2S(0, 0, true , LA[1], Ag, kta, 0)
    PHASE2S(2, 0, false, LA[1], Ag, kta, 1)
    PHASE2S(4, 0, false, LB[0], W,  ktb, 0)
    PHASE2N(6, 0)
    PHASE2S(0, 1, true , LA[0], Ag, ktb, 0)
    PHASE2S(2, 1, false, LA[0], Ag, ktb, 1)
    PHASE2S(4, 1, false, LB[1], W,  ktc, 0)
    PHASE2N(6, 1)
  }
  #undef PHASE2S
  #undef PHASE2N
  #undef PH2_CORE
  #undef PH2_TAIL
  #undef STG2

  #pragma unroll
  for (int mi = 0; mi < 8; ++mi)
    #pragma unroll
    for (int r = 0; r < 4; ++r) {
      const int row = m0 + wm*128 + mi*16 + (lane>>4)*4 + r;
      #pragma unroll
      for (int nj = 0; nj < 2; ++nj) {
        const int col = n0 + wn*32 + nj*16 + l15;
        cstore(&C[(size_t)row*N + col], acc[mi][nj][r]);
      }
    }
}

// Per (b,t): RMSNorm(HD) + RoPE IN PLACE. Q pre-multiplied by SCALE2_.
__global__ __launch_bounds__(256) void postproc(
    bf16* __restrict__ q, bf16* __restrict__ k,
    const float* __restrict__ qw, const float* __restrict__ kw)
{
  const int blk  = blockIdx.x;
  const int t    = blk & (T_-1);
  const int lane = threadIdx.x & 63;
  const int w    = threadIdx.x >> 6;

  const float inv = expf(-(float)lane * (9.210340371976184f / 64.f));
  const float ang = (float)t * inv;
  const float cw = cosf(ang), sw = sinf(ang);

  #pragma unroll
  for (int hi = 0; hi < 4; ++hi) {
    const int h = w + hi*4;
    bf16* row = q + (size_t)blk*(NH_*HD_) + h*HD_;
    float x1 = __bfloat162float(row[lane]);
    float x2 = __bfloat162float(row[lane+64]);
    float ss = x1*x1 + x2*x2;
    #pragma unroll
    for (int m = 1; m < 64; m <<= 1) ss += __shfl_xor(ss, m, 64);
    const float rs = rsqrtf(ss*(1.f/128.f) + 1e-6f);
    const float n1 = x1*rs*(1.f + qw[lane]), n2 = x2*rs*(1.f + qw[lane+64]);
    row[lane]    = __float2bfloat16((n1*cw - n2*sw) * SCALE2_);
    row[lane+64] = __float2bfloat16((n2*cw + n1*sw) * SCALE2_);
  }
  {
    bf16* row = k + (size_t)blk*(NKV_*HD_) + w*HD_;
    float x1 = __bfloat162float(row[lane]);
    float x2 = __bfloat162float(row[lane+64]);
    float ss = x1*x1 + x2*x2;
    #pragma unroll
    for (int m = 1; m < 64; m <<= 1) ss += __shfl_xor(ss, m, 64);
    const float rs = rsqrtf(ss*(1.f/128.f) + 1e-6f);
    const float n1 = x1*rs*(1.f + kw[lane]), n2 = x2*rs*(1.f + kw[lane+64]);
    row[lane]    = __float2bfloat16(n1*cw - n2*sw);
    row[lane+64] = __float2bfloat16(n2*cw + n1*sw);
  }
}

// v_raw [b*T+t][kvh*128+d]  ->  Vt [b][kvh][d][T]
__global__ __launch_bounds__(256) void vtrans(const bf16* __restrict__ vraw,
                                              bf16* __restrict__ Vt)
{
  __shared__ bf16 tile[64][65];
  const int t0 = blockIdx.x * 64;
  const int c0 = blockIdx.y * 64;
  const int b  = blockIdx.z;
  const int tx = threadIdx.x & 63;
  const int ty = threadIdx.x >> 6;
  const bf16* src = vraw + (size_t)b * T_ * (NKV_*HD_);
  bf16* dst       = Vt   + (size_t)b * (NKV_*HD_) * T_;
  #pragma unroll
  for (int i = 0; i < 16; ++i) {
    const int r = i*4 + ty;
    tile[r][tx] = src[(size_t)(t0 + r)*(NKV_*HD_) + c0 + tx];
  }
  __syncthreads();
  #pragma unroll
  for (int i = 0; i < 16; ++i) {
    const int r = i*4 + ty;
    dst[(size_t)(c0 + r)*T_ + t0 + tx] = tile[tx][r];
  }
}

// Flash attention v10: v9 + anti-paired block decode. Blocks [0,256):
// s = 63-(q>>2), kvh in {0,1}; blocks [256,512): s = q>>2, kvh in {2,3}.
// Under round-robin assignment CU c hosts one heavy + one light block with
// constant total work (~34 tiles) instead of 17..49.
__global__ __launch_bounds__(512, 4) void attn(
    const bf16* __restrict__ Q, const bf16* __restrict__ Kb,
    const bf16* __restrict__ Vt, bf16* __restrict__ att)
{
  const int id   = blockIdx.x;         // 0..511
  const int hlf  = id >> 8;            // 0 or 1
  const int q_   = id & 255;
  const int s    = hlf ? (q_ >> 2) : (63 - (q_ >> 2));
  const int sub  = (id & 3) | (hlf << 2);   // 0..7
  const int kvh  = sub >> 1;           // 0..3
  const int b    = sub & 1;            // 0..1
  const int tid = threadIdx.x, lane = tid & 63, w = tid >> 6;
  const int h   = kvh*4 + (w & 3);
  const int l15 = lane & 15;
  const int g   = lane >> 4;
  const int lr4 = g * 4;
  const int swz = l15 & 7;

  const int q0w = s*32 + (w >> 2)*16;
  const int nt  = (s >> 1) + 1;

  __shared__ bf16 Ks[2][64*128];
  __shared__ bf16 Vs[2][128*64];
  __shared__ bf16 Plds[8][16*64];

  const bf16* Kglob = Kb + (size_t)b*T_*(NKV_*HD_) + kvh*HD_;
  const bf16* Vglob = Vt + (size_t)(b*NKV_ + kvh)*HD_*T_;

  bh8 aQ[4];
  #pragma unroll
  for (int kk = 0; kk < 4; ++kk)
    aQ[kk] = *(const bh8*)&Q[(size_t)(b*T_ + q0w + l15)*(NH_*HD_) + h*HD_ + kk*32 + g*8];

  f32x4 acc[8] = {};
  float lL = 0.f;

  #define STAGE_KV(buf, kv0s)                                                   \
    {                                                                           \
      _Pragma("unroll")                                                         \
      for (int i = 0; i < 2; ++i) {                                             \
        const int o = i*512 + tid;                                              \
        const int r = o >> 4, sl = o & 15;                                      \
        gload16(Kglob + (size_t)((kv0s) + r)*(NKV_*HD_) + ((sl ^ (r & 7)) << 3),\
                &Ks[buf][o*8]);                                                 \
      }                                                                         \
      _Pragma("unroll")                                                         \
      for (int i = 0; i < 2; ++i) {                                             \
        const int o = i*512 + tid;                                              \
        const int d = o >> 3, sl = o & 7;                                       \
        gload16(Vglob + (size_t)d*T_ + (kv0s) + ((sl ^ (d & 7)) << 3),          \
                &Vs[buf][o*8]);                                                 \
      }                                                                         \
    }

  STAGE_KV(0, 0);
  asm volatile("s_waitcnt vmcnt(0)" ::: "memory");
  __syncthreads();

  for (int j = 0; j < nt; ++j) {
    const int cur = j & 1;
    const int kv0 = j*64;

    if (j + 1 < nt) STAGE_KV(cur ^ 1, kv0 + 64);

    f32x4 S[4] = {};
    #pragma unroll
    for (int jb = 0; jb < 4; ++jb)
      #pragma unroll
      for (int kk = 0; kk < 4; ++kk) {
        const bh8 kf = *(const bh8*)&Ks[cur][(jb*16 + l15)*128 + (((kk*4 + g) ^ swz) << 3)];
        S[jb] = __builtin_amdgcn_mfma_f32_16x16x32_bf16(kf, aQ[kk], S[jb], 0,0,0);
      }

    const bool diag = (j == nt - 1);
    float sv[16];
    float sum = 0.f;
    #pragma unroll
    for (int jb = 0; jb < 4; ++jb)
      #pragma unroll
      for (int r = 0; r < 4; ++r) {
        float sc = S[jb][r];
        if (diag && (kv0 + jb*16 + lr4 + r) > (q0w + l15)) sc = -1e30f;
        const float p = exp2f(sc);
        sv[jb*4 + r] = p;
        sum += p;
      }
    lL += sum;

    bf16* pl = Plds[w];
    #pragma unroll
    for (int jb = 0; jb < 4; ++jb) {
      bf16 pk[4];
      #pragma unroll
      for (int r = 0; r < 4; ++r) pk[r] = __float2bfloat16(sv[jb*4 + r]);
      *(us4*)((char*)pl + l15*128 + ((((jb<<1) | (g>>1)) ^ swz) << 4) + ((g&1) << 3))
          = *(const us4*)pk;
    }

    asm volatile("s_waitcnt lgkmcnt(0)" ::: "memory");
    __builtin_amdgcn_sched_barrier(0);

    const bh8 pa0 = *(const bh8*)((const char*)pl + l15*128 + (((g    ) ^ swz) << 4));
    const bh8 pa1 = *(const bh8*)((const char*)pl + l15*128 + (((4 + g) ^ swz) << 4));
    #pragma unroll
    for (int jd = 0; jd < 8; ++jd) {
      const bh8 vf0 = *(const bh8*)&Vs[cur][(jd*16 + l15)*64 + (((g    ) ^ swz) << 3)];
      const bh8 vf1 = *(const bh8*)&Vs[cur][(jd*16 + l15)*64 + (((4 + g) ^ swz) << 3)];
      acc[jd] = __builtin_amdgcn_mfma_f32_16x16x32_bf16(pa0, vf0, acc[jd], 0,0,0);
      acc[jd] = __builtin_amdgcn_mfma_f32_16x16x32_bf16(pa1, vf1, acc[jd], 0,0,0);
    }

    asm volatile("s_waitcnt vmcnt(0)" ::: "memory");
    __syncthreads();
  }
  #undef STAGE_KV

  lL += __shfl_xor(lL, 16, 64);
  lL += __shfl_xor(lL, 32, 64);
  float lar[4];
  #pragma unroll
  for (int r = 0; r < 4; ++r)
    lar[r] = __shfl(lL, (lane & 48) | (lr4 + r), 64);
  #pragma unroll
  for (int r = 0; r < 4; ++r) {
    const float inv = 1.f / lar[r];
    const int row = q0w + lr4 + r;
    bf16* orow = att + ((size_t)(b*T_ + row))*(NH_*HD_) + h*HD_;
    #pragma unroll
    for (int jd = 0; jd < 8; ++jd)
      orow[jd*16 + l15] = __float2bfloat16(acc[jd][r] * inv);
  }
}

extern "C" void kernel_launch(void* const* d_in, const int* in_sizes, int n_in,
                              void* d_out, int out_size, void* d_ws, size_t ws_size,
                              hipStream_t stream) {
  const float* x  = (const float*)d_in[0];
  const float* Wq = (const float*)d_in[1];
  const float* Wk = (const float*)d_in[2];
  const float* Wv = (const float*)d_in[3];
  const float* Wo = (const float*)d_in[4];
  const float* qw = (const float*)d_in[5];
  const float* kw = (const float*)d_in[6];
  float* out = (float*)d_out;

  char* ws = (char*)d_ws;
  bf16* xb   = (bf16*)(ws);                  // 16MB  (-> att later)
  bf16* Wqb  = (bf16*)(ws + (16u<<20));      // 8MB
  bf16* Wkb  = (bf16*)(ws + (24u<<20));      // 2MB
  bf16* Wvb  = (bf16*)(ws + (26u<<20));      // 2MB
  bf16* Wob  = (bf16*)(ws + (28u<<20));      // 8MB
  bf16* kbuf = (bf16*)(ws + (36u<<20));      // 4MB
  bf16* vraw = (bf16*)(ws + (40u<<20));      // 4MB
  bf16* Vt   = (bf16*)(ws + (44u<<20));      // 4MB
  bf16* att  = xb;
  bf16* qbuf = (bf16*)d_out;                 // Q scratch in d_out

  cvt32to16<<<dim3(2048), 256, 0, stream>>>(x, xb, M_*H_);
  cvtw<<<dim3(1280), 256, 0, stream>>>(Wq, Wqb, Wo, Wob, Wk, Wkb, Wv, Wvb);

  // fused QKV: 192 blocks (16m x 12n), XCD-chunked (cpx = 192/8 = 24)
  gemm256<bf16><<<dim3(192), 512, 0, stream>>>(xb, Wqb, Wkb, Wvb,
                                               qbuf, kbuf, vraw,
                                               2048, 12, 8, 10, 2048, 24);
  postproc<<<dim3(M_), 256, 0, stream>>>(qbuf, kbuf, qw, kw);
  vtrans<<<dim3(T_/64, (NKV_*HD_)/64, B_), 256, 0, stream>>>(vraw, Vt);
  attn<<<dim3(512), 512, 0, stream>>>(qbuf, kbuf, Vt, att);
  // O-proj: 256 blocks (16m x 16n), XCD-chunked (cpx = 256/8 = 32)
  gemm_n128<float><<<dim3(256), 512, 0, stream>>>(att, Wob, out, 2048, 16, 2048, 32);
}